// Round 1
// baseline (891.304 us; speedup 1.0000x reference)
//
#include <hip/hip_runtime.h>

#define N_NODESC 100000
#define N_EDGESC 1600000
#define E_TOTC   1700000
#define NB_SCAN  391   // ceil(100000/256)

// ------------------------------------------------------------------
// Preprocessing: build CSR (grouped by dst) of the edge list + self loops
// ------------------------------------------------------------------
__global__ void k_init(int* deg, int* rowptr) {
    int i = blockIdx.x * 256 + threadIdx.x;
    if (i < N_NODESC) deg[i] = 1;             // self-loop contributes 1
    if (i == 0) rowptr[N_NODESC] = E_TOTC;    // total is a compile-time constant
}

__global__ void k_hist(const int* __restrict__ ei, int* deg) {
    int e = blockIdx.x * 256 + threadIdx.x;
    if (e < N_EDGESC) atomicAdd(&deg[ei[N_EDGESC + e]], 1);
}

__global__ void k_scanA(const int* __restrict__ deg, int* partials) {
    __shared__ int sd[256];
    int t = threadIdx.x;
    int i = blockIdx.x * 256 + t;
    sd[t] = (i < N_NODESC) ? deg[i] : 0;
    __syncthreads();
    for (int off = 128; off > 0; off >>= 1) {
        if (t < off) sd[t] += sd[t + off];
        __syncthreads();
    }
    if (t == 0) partials[blockIdx.x] = sd[0];
}

__global__ void k_scanB(int* partials) {
    __shared__ int sd[512];
    int t = threadIdx.x;
    int v = (t < NB_SCAN) ? partials[t] : 0;
    sd[t] = v;
    __syncthreads();
    for (int off = 1; off < 512; off <<= 1) {
        int x = (t >= off) ? sd[t - off] : 0;
        __syncthreads();
        sd[t] += x;
        __syncthreads();
    }
    if (t < NB_SCAN) partials[t] = sd[t] - v;  // exclusive scan of block sums
}

__global__ void k_scanC(const int* __restrict__ deg, const int* __restrict__ partials,
                        int* rowptr, int* cursor) {
    __shared__ int sd[256];
    int t = threadIdx.x;
    int i = blockIdx.x * 256 + t;
    int v = (i < N_NODESC) ? deg[i] : 0;
    sd[t] = v;
    __syncthreads();
    for (int off = 1; off < 256; off <<= 1) {
        int x = (t >= off) ? sd[t - off] : 0;
        __syncthreads();
        sd[t] += x;
        __syncthreads();
    }
    int excl = sd[t] - v + partials[blockIdx.x];
    if (i < N_NODESC) { rowptr[i] = excl; cursor[i] = excl; }
}

__global__ void k_scatter(const int* __restrict__ ei, int* cursor, int* __restrict__ ssrc) {
    int e = blockIdx.x * 256 + threadIdx.x;
    if (e >= E_TOTC) return;
    int s, d;
    if (e < N_EDGESC) { s = ei[e]; d = ei[N_EDGESC + e]; }
    else { s = d = e - N_EDGESC; }
    int pos = atomicAdd(&cursor[d], 1);
    ssrc[pos] = s;
}

// ------------------------------------------------------------------
// f32 GEMM: C[M,128] = A[M,128] @ W[128,128]. BM=64 per block, 256 thr,
// per-thread 4 rows x 8 cols. A-tile transposed in LDS (conflict-free:
// writes are consecutive-r, reads are 16-lane broadcasts of b128).
// ------------------------------------------------------------------
__global__ __launch_bounds__(256) void k_gemm(const float* __restrict__ A,
                                              const float* __restrict__ W,
                                              float* __restrict__ C, int M) {
    __shared__ float Xt[128][64];  // [k][m] 32 KB
    int t = threadIdx.x;
    int mbase = blockIdx.x * 64;
    {
        int r = t & 63;
        int row = mbase + r;
        if (row >= M) row = 0;  // clamp; stores are guarded
        const float4* A4 = (const float4*)A;
#pragma unroll
        for (int j = 0; j < 8; ++j) {
            int k4 = (t >> 6) + j * 4;
            float4 v = A4[(size_t)row * 32 + k4];
            int kf = k4 * 4;
            Xt[kf + 0][r] = v.x;
            Xt[kf + 1][r] = v.y;
            Xt[kf + 2][r] = v.z;
            Xt[kf + 3][r] = v.w;
        }
    }
    __syncthreads();
    int m0 = (t >> 4) * 4;    // 0..60
    int n4 = (t & 15) * 2;    // float4 column index (cols n4*4..n4*4+7)
    float acc[4][8];
#pragma unroll
    for (int i = 0; i < 4; ++i)
#pragma unroll
        for (int j = 0; j < 8; ++j) acc[i][j] = 0.f;
    const float4* W4 = (const float4*)W;
#pragma unroll 4
    for (int k = 0; k < 128; ++k) {
        float4 b0 = W4[k * 32 + n4];
        float4 b1 = W4[k * 32 + n4 + 1];
        float4 a = *(const float4*)&Xt[k][m0];
        float av[4] = {a.x, a.y, a.z, a.w};
        float bv[8] = {b0.x, b0.y, b0.z, b0.w, b1.x, b1.y, b1.z, b1.w};
#pragma unroll
        for (int i = 0; i < 4; ++i)
#pragma unroll
            for (int j = 0; j < 8; ++j) acc[i][j] += av[i] * bv[j];
    }
    float4* C4 = (float4*)C;
#pragma unroll
    for (int i = 0; i < 4; ++i) {
        int m = mbase + m0 + i;
        if (m < M) {
            float4 o0 = {acc[i][0], acc[i][1], acc[i][2], acc[i][3]};
            float4 o1 = {acc[i][4], acc[i][5], acc[i][6], acc[i][7]};
            C4[(size_t)m * 32 + n4]     = o0;
            C4[(size_t)m * 32 + n4 + 1] = o1;
        }
    }
}

// ------------------------------------------------------------------
// Per-(node,head) attention logits: al_src[n,h] = h[n,h,:]·a_src[h,:]
// ------------------------------------------------------------------
__global__ void k_al(const float* __restrict__ h, const float* __restrict__ a_src,
                     const float* __restrict__ a_dst, float* __restrict__ als,
                     float* __restrict__ ald) {
    int i = blockIdx.x * 256 + threadIdx.x;   // i = node*8 + head
    if (i >= N_NODESC * 8) return;
    int hd = i & 7;
    const float4* hv  = (const float4*)(h + (size_t)i * 16);
    const float4* as4 = (const float4*)(a_src + hd * 16);
    const float4* ad4 = (const float4*)(a_dst + hd * 16);
    float ds = 0.f, dd = 0.f;
#pragma unroll
    for (int j = 0; j < 4; ++j) {
        float4 a = hv[j], b = as4[j], c = ad4[j];
        ds += a.x * b.x + a.y * b.y + a.z * b.z + a.w * b.w;
        dd += a.x * c.x + a.y * c.y + a.z * c.z + a.w * c.w;
    }
    als[i] = ds;
    ald[i] = dd;
}

// ------------------------------------------------------------------
// Segment softmax + weighted aggregation. One wave per dst node.
// Pass A: online (m,s) per head over incoming edges + butterfly merge.
// Pass B: 2 edges/iter (half-wave each, float4/lane), combine via xor-32.
// ------------------------------------------------------------------
__global__ __launch_bounds__(256) void k_attn(const float* __restrict__ h,
                                              const float* __restrict__ als,
                                              const float* __restrict__ ald,
                                              const int* __restrict__ rowptr,
                                              const int* __restrict__ ssrc,
                                              const float* __restrict__ bias,
                                              float* __restrict__ out,
                                              int n, int do_relu) {
    int wid  = (blockIdx.x * blockDim.x + threadIdx.x) >> 6;
    int lane = threadIdx.x & 63;
    if (wid >= n) return;
    int start = rowptr[wid];
    int end   = rowptr[wid + 1];

    float m[8], s[8];
#pragma unroll
    for (int hh = 0; hh < 8; ++hh) { m[hh] = -1e30f; s[hh] = 0.f; }

    const float4* ald4 = (const float4*)(ald + (size_t)wid * 8);
    float4 dlo = ald4[0], dhi = ald4[1];
    float aldv[8] = {dlo.x, dlo.y, dlo.z, dlo.w, dhi.x, dhi.y, dhi.z, dhi.w};

    const float4* als4 = (const float4*)als;
    for (int e = start + lane; e < end; e += 64) {
        int src = ssrc[e];
        float4 slo = als4[(size_t)src * 2];
        float4 shi = als4[(size_t)src * 2 + 1];
        float alsv[8] = {slo.x, slo.y, slo.z, slo.w, shi.x, shi.y, shi.z, shi.w};
#pragma unroll
        for (int hh = 0; hh < 8; ++hh) {
            float xv = alsv[hh] + aldv[hh];
            float el = xv >= 0.f ? xv : 0.2f * xv;
            float nm = fmaxf(m[hh], el);
            s[hh] = s[hh] * __expf(m[hh] - nm) + __expf(el - nm);
            m[hh] = nm;
        }
    }
    // butterfly merge of (m,s) across 64 lanes
#pragma unroll
    for (int off = 32; off > 0; off >>= 1) {
#pragma unroll
        for (int hh = 0; hh < 8; ++hh) {
            float om = __shfl_xor(m[hh], off, 64);
            float os = __shfl_xor(s[hh], off, 64);
            float nm = fmaxf(m[hh], om);
            s[hh] = s[hh] * __expf(m[hh] - nm) + os * __expf(om - nm);
            m[hh] = nm;
        }
    }

    int half = lane >> 5;
    int q    = lane & 31;   // float4 index within the 128-float row
    int hd   = q >> 2;      // head of this lane's features
    float mh = m[0], sh = s[0], ah = aldv[0];
#pragma unroll
    for (int hh = 1; hh < 8; ++hh) {
        if (hd == hh) { mh = m[hh]; sh = s[hh]; ah = aldv[hh]; }
    }
    float invs = 1.0f / (sh + 1e-16f);

    float4 acc = {0.f, 0.f, 0.f, 0.f};
    const float4* h4 = (const float4*)h;
    for (int e0 = start; e0 < end; e0 += 2) {
        int e = e0 + half;
        bool valid = (e < end);
        int src = ssrc[valid ? e : start];
        float xv = als[(size_t)src * 8 + hd] + ah;
        float el = xv >= 0.f ? xv : 0.2f * xv;
        float w  = valid ? __expf(el - mh) * invs : 0.f;
        float4 hv = h4[(size_t)src * 32 + q];
        acc.x += w * hv.x;
        acc.y += w * hv.y;
        acc.z += w * hv.z;
        acc.w += w * hv.w;
    }
    acc.x += __shfl_xor(acc.x, 32, 64);
    acc.y += __shfl_xor(acc.y, 32, 64);
    acc.z += __shfl_xor(acc.z, 32, 64);
    acc.w += __shfl_xor(acc.w, 32, 64);
    if (lane < 32) {
        float4 bv = ((const float4*)bias)[q];
        float4 o = {acc.x + bv.x, acc.y + bv.y, acc.z + bv.z, acc.w + bv.w};
        if (do_relu) {
            o.x = fmaxf(o.x, 0.f); o.y = fmaxf(o.y, 0.f);
            o.z = fmaxf(o.z, 0.f); o.w = fmaxf(o.w, 0.f);
        }
        ((float4*)out)[(size_t)wid * 32 + q] = o;
    }
}

// ------------------------------------------------------------------
// Prediction heads: one wave per (sampled row). Computes both wy1 and wy0
// dots in one pass. Output order: y1, yc0, y0, yc1.
// ------------------------------------------------------------------
__global__ __launch_bounds__(256) void k_heads(const float* __restrict__ z,
                                               const int* __restrict__ tidx,
                                               const int* __restrict__ cidx,
                                               const float* __restrict__ wy1,
                                               const float* __restrict__ by1,
                                               const float* __restrict__ wy0,
                                               const float* __restrict__ by0,
                                               float* __restrict__ out, int M) {
    int wid  = (blockIdx.x * blockDim.x + threadIdx.x) >> 6;
    int lane = threadIdx.x & 63;
    if (wid >= 2 * M) return;
    int which = (wid >= M) ? 1 : 0;
    int i = wid - which * M;
    int idx = which ? cidx[i] : tidx[i];
    float2 zv = ((const float2*)(z + (size_t)idx * 128))[lane];
    float2 w1 = ((const float2*)wy1)[lane];
    float2 w0 = ((const float2*)wy0)[lane];
    float d1 = zv.x * w1.x + zv.y * w1.y;
    float d0 = zv.x * w0.x + zv.y * w0.y;
#pragma unroll
    for (int off = 32; off > 0; off >>= 1) {
        d1 += __shfl_xor(d1, off, 64);
        d0 += __shfl_xor(d0, off, 64);
    }
    if (lane == 0) {
        float y1v = d1 + by1[0]; y1v = y1v >= 0.f ? y1v : 0.01f * y1v;
        float y0v = d0 + by0[0]; y0v = y0v >= 0.f ? y0v : 0.01f * y0v;
        if (which == 0) { out[i] = y1v; out[M + i] = y0v; }
        else            { out[2 * M + i] = y0v; out[3 * M + i] = y1v; }
    }
}

// ------------------------------------------------------------------
extern "C" void kernel_launch(void* const* d_in, const int* in_sizes, int n_in,
                              void* d_out, int out_size, void* d_ws, size_t ws_size,
                              hipStream_t stream) {
    const float* x   = (const float*)d_in[0];
    const int*   ei  = (const int*)d_in[1];
    const int*   tix = (const int*)d_in[2];
    const int*   cix = (const int*)d_in[3];
    const float* W1  = (const float*)d_in[4];
    const float* as1 = (const float*)d_in[5];
    const float* ad1 = (const float*)d_in[6];
    const float* b1  = (const float*)d_in[7];
    const float* W2  = (const float*)d_in[8];
    const float* as2 = (const float*)d_in[9];
    const float* ad2 = (const float*)d_in[10];
    const float* b2  = (const float*)d_in[11];
    const float* wy1 = (const float*)d_in[12];
    const float* by1 = (const float*)d_in[13];
    const float* wy0 = (const float*)d_in[14];
    const float* by0 = (const float*)d_in[15];
    float* out = (float*)d_out;

    // workspace layout (~112 MiB)
    float* h_buf = (float*)d_ws;              // 12.8M f  (h of current layer)
    float* z_buf = h_buf + 12800000;          // 12.8M f  (xZ1)
    float* als   = z_buf + 12800000;          // 800k f
    float* ald   = als + 800000;              // 800k f
    int* deg     = (int*)(ald + 800000);      // 100001
    int* rowptr  = deg + 100001;              // 100001
    int* cursor  = rowptr + 100001;           // 100001
    int* parts   = cursor + 100001;           // 512
    int* ssrc    = parts + 512;               // 1.7M

    dim3 B(256);
    // ---- CSR build (recomputed every call; ws is re-poisoned) ----
    k_init<<<(N_NODESC + 255) / 256, B, 0, stream>>>(deg, rowptr);
    k_hist<<<(N_EDGESC + 255) / 256, B, 0, stream>>>(ei, deg);
    k_scanA<<<NB_SCAN, B, 0, stream>>>(deg, parts);
    k_scanB<<<1, dim3(512), 0, stream>>>(parts);
    k_scanC<<<NB_SCAN, B, 0, stream>>>(deg, parts, rowptr, cursor);
    k_scatter<<<(E_TOTC + 255) / 256, B, 0, stream>>>(ei, cursor, ssrc);
    // ---- layer 1: h1 = x@W1; xZ1 = relu(GAT(h1) + b1) ----
    k_gemm<<<(N_NODESC + 63) / 64, B, 0, stream>>>(x, W1, h_buf, N_NODESC);
    k_al<<<(N_NODESC * 8 + 255) / 256, B, 0, stream>>>(h_buf, as1, ad1, als, ald);
    k_attn<<<(N_NODESC + 3) / 4, B, 0, stream>>>(h_buf, als, ald, rowptr, ssrc, b1,
                                                 z_buf, N_NODESC, 1);
    // ---- layer 2: h2 = xZ1@W2; xZ2 = GAT(h2) + b2 -> d_out[80000:] ----
    k_gemm<<<(N_NODESC + 63) / 64, B, 0, stream>>>(z_buf, W2, h_buf, N_NODESC);
    k_al<<<(N_NODESC * 8 + 255) / 256, B, 0, stream>>>(h_buf, as2, ad2, als, ald);
    k_attn<<<(N_NODESC + 3) / 4, B, 0, stream>>>(h_buf, als, ald, rowptr, ssrc, b2,
                                                 out + 80000, N_NODESC, 0);
    // ---- heads ----
    k_heads<<<(2 * 20000 * 64) / 256, B, 0, stream>>>(out + 80000, tix, cix,
                                                      wy1, by1, wy0, by0, out, 20000);
}

// Round 2
// 857.125 us; speedup vs baseline: 1.0399x; 1.0399x over previous
//
#include <hip/hip_runtime.h>

#define N_NODESC 100000
#define N_EDGESC 1600000
#define E_TOTC   1700000
#define NB_SCAN  391   // ceil(100000/256)

// ------------------------------------------------------------------
// Preprocessing: build CSR (grouped by dst) of the edge list + self loops
// ------------------------------------------------------------------
__global__ void k_init(int* deg, int* rowptr) {
    int i = blockIdx.x * 256 + threadIdx.x;
    if (i < N_NODESC) deg[i] = 1;             // self-loop contributes 1
    if (i == 0) rowptr[N_NODESC] = E_TOTC;    // total is a compile-time constant
}

__global__ void k_hist(const int* __restrict__ ei, int* deg) {
    int e = blockIdx.x * 256 + threadIdx.x;
    if (e < N_EDGESC) atomicAdd(&deg[ei[N_EDGESC + e]], 1);
}

__global__ void k_scanA(const int* __restrict__ deg, int* partials) {
    __shared__ int sd[256];
    int t = threadIdx.x;
    int i = blockIdx.x * 256 + t;
    sd[t] = (i < N_NODESC) ? deg[i] : 0;
    __syncthreads();
    for (int off = 128; off > 0; off >>= 1) {
        if (t < off) sd[t] += sd[t + off];
        __syncthreads();
    }
    if (t == 0) partials[blockIdx.x] = sd[0];
}

__global__ void k_scanB(int* partials) {
    __shared__ int sd[512];
    int t = threadIdx.x;
    int v = (t < NB_SCAN) ? partials[t] : 0;
    sd[t] = v;
    __syncthreads();
    for (int off = 1; off < 512; off <<= 1) {
        int x = (t >= off) ? sd[t - off] : 0;
        __syncthreads();
        sd[t] += x;
        __syncthreads();
    }
    if (t < NB_SCAN) partials[t] = sd[t] - v;  // exclusive scan of block sums
}

__global__ void k_scanC(const int* __restrict__ deg, const int* __restrict__ partials,
                        int* rowptr, int* cursor) {
    __shared__ int sd[256];
    int t = threadIdx.x;
    int i = blockIdx.x * 256 + t;
    int v = (i < N_NODESC) ? deg[i] : 0;
    sd[t] = v;
    __syncthreads();
    for (int off = 1; off < 256; off <<= 1) {
        int x = (t >= off) ? sd[t - off] : 0;
        __syncthreads();
        sd[t] += x;
        __syncthreads();
    }
    int excl = sd[t] - v + partials[blockIdx.x];
    if (i < N_NODESC) { rowptr[i] = excl; cursor[i] = excl; }
}

__global__ void k_scatter(const int* __restrict__ ei, int* cursor, int* __restrict__ ssrc) {
    int e = blockIdx.x * 256 + threadIdx.x;
    if (e >= E_TOTC) return;
    int s, d;
    if (e < N_EDGESC) { s = ei[e]; d = ei[N_EDGESC + e]; }
    else { s = d = e - N_EDGESC; }
    int pos = atomicAdd(&cursor[d], 1);
    ssrc[pos] = s;
}

// ------------------------------------------------------------------
// f32 GEMM: C[M,128] = A[M,128] @ W[128,128]. BM=64 per block, 256 thr.
// ------------------------------------------------------------------
__global__ __launch_bounds__(256) void k_gemm(const float* __restrict__ A,
                                              const float* __restrict__ W,
                                              float* __restrict__ C, int M) {
    __shared__ float Xt[128][64];  // [k][m] 32 KB
    int t = threadIdx.x;
    int mbase = blockIdx.x * 64;
    {
        int r = t & 63;
        int row = mbase + r;
        if (row >= M) row = 0;  // clamp; stores are guarded
        const float4* A4 = (const float4*)A;
#pragma unroll
        for (int j = 0; j < 8; ++j) {
            int k4 = (t >> 6) + j * 4;
            float4 v = A4[(size_t)row * 32 + k4];
            int kf = k4 * 4;
            Xt[kf + 0][r] = v.x;
            Xt[kf + 1][r] = v.y;
            Xt[kf + 2][r] = v.z;
            Xt[kf + 3][r] = v.w;
        }
    }
    __syncthreads();
    int m0 = (t >> 4) * 4;    // 0..60
    int n4 = (t & 15) * 2;    // float4 column index
    float acc[4][8];
#pragma unroll
    for (int i = 0; i < 4; ++i)
#pragma unroll
        for (int j = 0; j < 8; ++j) acc[i][j] = 0.f;
    const float4* W4 = (const float4*)W;
#pragma unroll 4
    for (int k = 0; k < 128; ++k) {
        float4 b0 = W4[k * 32 + n4];
        float4 b1 = W4[k * 32 + n4 + 1];
        float4 a = *(const float4*)&Xt[k][m0];
        float av[4] = {a.x, a.y, a.z, a.w};
        float bv[8] = {b0.x, b0.y, b0.z, b0.w, b1.x, b1.y, b1.z, b1.w};
#pragma unroll
        for (int i = 0; i < 4; ++i)
#pragma unroll
            for (int j = 0; j < 8; ++j) acc[i][j] += av[i] * bv[j];
    }
    float4* C4 = (float4*)C;
#pragma unroll
    for (int i = 0; i < 4; ++i) {
        int m = mbase + m0 + i;
        if (m < M) {
            float4 o0 = {acc[i][0], acc[i][1], acc[i][2], acc[i][3]};
            float4 o1 = {acc[i][4], acc[i][5], acc[i][6], acc[i][7]};
            C4[(size_t)m * 32 + n4]     = o0;
            C4[(size_t)m * 32 + n4 + 1] = o1;
        }
    }
}

// ------------------------------------------------------------------
// Per-(node,head) attention logits
// ------------------------------------------------------------------
__global__ void k_al(const float* __restrict__ h, const float* __restrict__ a_src,
                     const float* __restrict__ a_dst, float* __restrict__ als,
                     float* __restrict__ ald) {
    int i = blockIdx.x * 256 + threadIdx.x;   // i = node*8 + head
    if (i >= N_NODESC * 8) return;
    int hd = i & 7;
    const float4* hv  = (const float4*)(h + (size_t)i * 16);
    const float4* as4 = (const float4*)(a_src + hd * 16);
    const float4* ad4 = (const float4*)(a_dst + hd * 16);
    float ds = 0.f, dd = 0.f;
#pragma unroll
    for (int j = 0; j < 4; ++j) {
        float4 a = hv[j], b = as4[j], c = ad4[j];
        ds += a.x * b.x + a.y * b.y + a.z * b.z + a.w * b.w;
        dd += a.x * c.x + a.y * c.y + a.z * c.z + a.w * c.w;
    }
    als[i] = ds;
    ald[i] = dd;
}

// ------------------------------------------------------------------
// Segment softmax stats, head-per-lane. Each wave = 8 nodes x 8 heads;
// lane = group*8 + head; each lane loops sequentially over its node's
// incoming edges. Uses monotonicity: max(leaky(as+ad)) = leaky(max(as)+ad).
// Writes m[n,h] and 1/s[n,h]. No cross-lane reduction needed at all.
// ------------------------------------------------------------------
__global__ __launch_bounds__(256) void k_ms(const float* __restrict__ als,
                                            const float* __restrict__ ald,
                                            const int* __restrict__ rowptr,
                                            const int* __restrict__ ssrc,
                                            float* __restrict__ mbuf,
                                            float* __restrict__ isbuf, int n) {
    int wid  = (blockIdx.x * blockDim.x + threadIdx.x) >> 6;
    int lane = threadIdx.x & 63;
    int g = lane >> 3, hh = lane & 7;
    int node = wid * 8 + g;
    bool act = node < n;
    int nc = act ? node : 0;
    int start = rowptr[nc];
    int end   = rowptr[nc + 1];
    float av  = ald[(size_t)nc * 8 + hh];

    float mv = -1e30f;
    for (int e = start; e < end; ++e) {
        int src = ssrc[e];
        mv = fmaxf(mv, als[(size_t)src * 8 + hh]);
    }
    float mm = mv + av;
    mm = mm >= 0.f ? mm : 0.2f * mm;

    float s = 0.f;
    for (int e = start; e < end; ++e) {
        int src = ssrc[e];
        float xv = als[(size_t)src * 8 + hh] + av;
        float el = xv >= 0.f ? xv : 0.2f * xv;
        s += __expf(el - mm);
    }
    if (act) {
        mbuf[(size_t)node * 8 + hh]  = mm;
        isbuf[(size_t)node * 8 + hh] = 1.0f / (s + 1e-16f);
    }
}

// ------------------------------------------------------------------
// Weighted aggregation: one wave per dst node, 4 edges/iter (two
// independent half-wave gathers in flight). w recomputed from L2-hot als.
// ------------------------------------------------------------------
__global__ __launch_bounds__(256) void k_agg(const float* __restrict__ h,
                                             const float* __restrict__ als,
                                             const float* __restrict__ ald,
                                             const float* __restrict__ mbuf,
                                             const float* __restrict__ isbuf,
                                             const int* __restrict__ rowptr,
                                             const int* __restrict__ ssrc,
                                             const float* __restrict__ bias,
                                             float* __restrict__ out,
                                             int n, int do_relu) {
    int wid  = (blockIdx.x * blockDim.x + threadIdx.x) >> 6;
    int lane = threadIdx.x & 63;
    if (wid >= n) return;
    int start = rowptr[wid];
    int end   = rowptr[wid + 1];
    int half = lane >> 5;
    int q    = lane & 31;   // float4 index within the 128-float row
    int hd   = q >> 2;      // head for this lane's features

    float mh  = mbuf[(size_t)wid * 8 + hd];
    float ish = isbuf[(size_t)wid * 8 + hd];
    float ah  = ald[(size_t)wid * 8 + hd];

    float4 acc0 = {0.f, 0.f, 0.f, 0.f};
    float4 acc1 = {0.f, 0.f, 0.f, 0.f};
    const float4* h4 = (const float4*)h;

    for (int e0 = start; e0 < end; e0 += 4) {
        int ea = e0 + half;
        int eb = e0 + 2 + half;
        bool va = ea < end, vb = eb < end;
        int sa = ssrc[va ? ea : start];
        int sb = ssrc[vb ? eb : start];
        float4 hva = h4[(size_t)sa * 32 + q];
        float4 hvb = h4[(size_t)sb * 32 + q];
        float xa = als[(size_t)sa * 8 + hd] + ah;
        float xb = als[(size_t)sb * 8 + hd] + ah;
        float ela = xa >= 0.f ? xa : 0.2f * xa;
        float elb = xb >= 0.f ? xb : 0.2f * xb;
        float wa = va ? __expf(ela - mh) : 0.f;
        float wb = vb ? __expf(elb - mh) : 0.f;
        acc0.x += wa * hva.x; acc0.y += wa * hva.y;
        acc0.z += wa * hva.z; acc0.w += wa * hva.w;
        acc1.x += wb * hvb.x; acc1.y += wb * hvb.y;
        acc1.z += wb * hvb.z; acc1.w += wb * hvb.w;
    }
    float4 acc = {acc0.x + acc1.x, acc0.y + acc1.y,
                  acc0.z + acc1.z, acc0.w + acc1.w};
    acc.x += __shfl_xor(acc.x, 32, 64);
    acc.y += __shfl_xor(acc.y, 32, 64);
    acc.z += __shfl_xor(acc.z, 32, 64);
    acc.w += __shfl_xor(acc.w, 32, 64);
    if (lane < 32) {
        float4 bv = ((const float4*)bias)[q];
        float4 o = {acc.x * ish + bv.x, acc.y * ish + bv.y,
                    acc.z * ish + bv.z, acc.w * ish + bv.w};
        if (do_relu) {
            o.x = fmaxf(o.x, 0.f); o.y = fmaxf(o.y, 0.f);
            o.z = fmaxf(o.z, 0.f); o.w = fmaxf(o.w, 0.f);
        }
        ((float4*)out)[(size_t)wid * 32 + q] = o;
    }
}

// ------------------------------------------------------------------
// Prediction heads
// ------------------------------------------------------------------
__global__ __launch_bounds__(256) void k_heads(const float* __restrict__ z,
                                               const int* __restrict__ tidx,
                                               const int* __restrict__ cidx,
                                               const float* __restrict__ wy1,
                                               const float* __restrict__ by1,
                                               const float* __restrict__ wy0,
                                               const float* __restrict__ by0,
                                               float* __restrict__ out, int M) {
    int wid  = (blockIdx.x * blockDim.x + threadIdx.x) >> 6;
    int lane = threadIdx.x & 63;
    if (wid >= 2 * M) return;
    int which = (wid >= M) ? 1 : 0;
    int i = wid - which * M;
    int idx = which ? cidx[i] : tidx[i];
    float2 zv = ((const float2*)(z + (size_t)idx * 128))[lane];
    float2 w1 = ((const float2*)wy1)[lane];
    float2 w0 = ((const float2*)wy0)[lane];
    float d1 = zv.x * w1.x + zv.y * w1.y;
    float d0 = zv.x * w0.x + zv.y * w0.y;
#pragma unroll
    for (int off = 32; off > 0; off >>= 1) {
        d1 += __shfl_xor(d1, off, 64);
        d0 += __shfl_xor(d0, off, 64);
    }
    if (lane == 0) {
        float y1v = d1 + by1[0]; y1v = y1v >= 0.f ? y1v : 0.01f * y1v;
        float y0v = d0 + by0[0]; y0v = y0v >= 0.f ? y0v : 0.01f * y0v;
        if (which == 0) { out[i] = y1v; out[M + i] = y0v; }
        else            { out[2 * M + i] = y0v; out[3 * M + i] = y1v; }
    }
}

// ------------------------------------------------------------------
extern "C" void kernel_launch(void* const* d_in, const int* in_sizes, int n_in,
                              void* d_out, int out_size, void* d_ws, size_t ws_size,
                              hipStream_t stream) {
    const float* x   = (const float*)d_in[0];
    const int*   ei  = (const int*)d_in[1];
    const int*   tix = (const int*)d_in[2];
    const int*   cix = (const int*)d_in[3];
    const float* W1  = (const float*)d_in[4];
    const float* as1 = (const float*)d_in[5];
    const float* ad1 = (const float*)d_in[6];
    const float* b1  = (const float*)d_in[7];
    const float* W2  = (const float*)d_in[8];
    const float* as2 = (const float*)d_in[9];
    const float* ad2 = (const float*)d_in[10];
    const float* b2  = (const float*)d_in[11];
    const float* wy1 = (const float*)d_in[12];
    const float* by1 = (const float*)d_in[13];
    const float* wy0 = (const float*)d_in[14];
    const float* by0 = (const float*)d_in[15];
    float* out = (float*)d_out;

    // workspace layout
    float* h_buf = (float*)d_ws;              // 12.8M f
    float* z_buf = h_buf + 12800000;          // 12.8M f
    float* als   = z_buf + 12800000;          // 800k f
    float* ald   = als + 800000;              // 800k f
    float* mbuf  = ald + 800000;              // 800k f
    float* isbuf = mbuf + 800000;             // 800k f
    int* deg     = (int*)(isbuf + 800000);    // 100001
    int* rowptr  = deg + 100001;              // 100001
    int* cursor  = rowptr + 100001;           // 100001
    int* parts   = cursor + 100001;           // 512
    int* ssrc    = parts + 512;               // 1.7M

    dim3 B(256);
    // ---- CSR build ----
    k_init<<<(N_NODESC + 255) / 256, B, 0, stream>>>(deg, rowptr);
    k_hist<<<(N_EDGESC + 255) / 256, B, 0, stream>>>(ei, deg);
    k_scanA<<<NB_SCAN, B, 0, stream>>>(deg, parts);
    k_scanB<<<1, dim3(512), 0, stream>>>(parts);
    k_scanC<<<NB_SCAN, B, 0, stream>>>(deg, parts, rowptr, cursor);
    k_scatter<<<(E_TOTC + 255) / 256, B, 0, stream>>>(ei, cursor, ssrc);
    // ---- layer 1 ----
    k_gemm<<<(N_NODESC + 63) / 64, B, 0, stream>>>(x, W1, h_buf, N_NODESC);
    k_al<<<(N_NODESC * 8 + 255) / 256, B, 0, stream>>>(h_buf, as1, ad1, als, ald);
    k_ms<<<(N_NODESC + 31) / 32, B, 0, stream>>>(als, ald, rowptr, ssrc, mbuf, isbuf, N_NODESC);
    k_agg<<<(N_NODESC + 3) / 4, B, 0, stream>>>(h_buf, als, ald, mbuf, isbuf, rowptr, ssrc,
                                                b1, z_buf, N_NODESC, 1);
    // ---- layer 2 ----
    k_gemm<<<(N_NODESC + 63) / 64, B, 0, stream>>>(z_buf, W2, h_buf, N_NODESC);
    k_al<<<(N_NODESC * 8 + 255) / 256, B, 0, stream>>>(h_buf, as2, ad2, als, ald);
    k_ms<<<(N_NODESC + 31) / 32, B, 0, stream>>>(als, ald, rowptr, ssrc, mbuf, isbuf, N_NODESC);
    k_agg<<<(N_NODESC + 3) / 4, B, 0, stream>>>(h_buf, als, ald, mbuf, isbuf, rowptr, ssrc,
                                                b2, out + 80000, N_NODESC, 0);
    // ---- heads ----
    k_heads<<<(2 * 20000 * 64) / 256, B, 0, stream>>>(out + 80000, tix, cix,
                                                      wy1, by1, wy0, by0, out, 20000);
}

// Round 3
// 698.378 us; speedup vs baseline: 1.2762x; 1.2273x over previous
//
#include <hip/hip_runtime.h>

#define N_NODESC 100000
#define N_EDGESC 1600000
#define E_TOTC   1700000
#define NB_SCAN  391   // ceil(100000/256)

__device__ inline unsigned bf16rne(float x) {
    unsigned u = __float_as_uint(x);
    return (u + 0x7fffu + ((u >> 16) & 1u)) >> 16;
}

// ------------------------------------------------------------------
// CSR build (grouped by dst) of edge list + self loops
// ------------------------------------------------------------------
__global__ void k_init(int* deg, int* rowptr) {
    int i = blockIdx.x * 256 + threadIdx.x;
    if (i < N_NODESC) deg[i] = 1;             // self-loop contributes 1
    if (i == 0) rowptr[N_NODESC] = E_TOTC;
}

__global__ void k_hist(const int* __restrict__ ei, int* deg) {
    int e = blockIdx.x * 256 + threadIdx.x;
    if (e < N_EDGESC) atomicAdd(&deg[ei[N_EDGESC + e]], 1);
}

__global__ void k_scanA(const int* __restrict__ deg, int* partials) {
    __shared__ int sd[256];
    int t = threadIdx.x;
    int i = blockIdx.x * 256 + t;
    sd[t] = (i < N_NODESC) ? deg[i] : 0;
    __syncthreads();
    for (int off = 128; off > 0; off >>= 1) {
        if (t < off) sd[t] += sd[t + off];
        __syncthreads();
    }
    if (t == 0) partials[blockIdx.x] = sd[0];
}

__global__ void k_scanB(int* partials) {
    __shared__ int sd[512];
    int t = threadIdx.x;
    int v = (t < NB_SCAN) ? partials[t] : 0;
    sd[t] = v;
    __syncthreads();
    for (int off = 1; off < 512; off <<= 1) {
        int x = (t >= off) ? sd[t - off] : 0;
        __syncthreads();
        sd[t] += x;
        __syncthreads();
    }
    if (t < NB_SCAN) partials[t] = sd[t] - v;  // exclusive scan of block sums
}

__global__ void k_scanC(const int* __restrict__ deg, const int* __restrict__ partials,
                        int* rowptr, int* cursor) {
    __shared__ int sd[256];
    int t = threadIdx.x;
    int i = blockIdx.x * 256 + t;
    int v = (i < N_NODESC) ? deg[i] : 0;
    sd[t] = v;
    __syncthreads();
    for (int off = 1; off < 256; off <<= 1) {
        int x = (t >= off) ? sd[t - off] : 0;
        __syncthreads();
        sd[t] += x;
        __syncthreads();
    }
    int excl = sd[t] - v + partials[blockIdx.x];
    if (i < N_NODESC) { rowptr[i] = excl; cursor[i] = excl; }
}

__global__ void k_scatter(const int* __restrict__ ei, int* cursor, int* __restrict__ ssrc) {
    int e = blockIdx.x * 256 + threadIdx.x;
    if (e >= E_TOTC) return;
    int s, d;
    if (e < N_EDGESC) { s = ei[e]; d = ei[N_EDGESC + e]; }
    else { s = d = e - N_EDGESC; }
    int pos = atomicAdd(&cursor[d], 1);
    ssrc[pos] = s;
}

// ------------------------------------------------------------------
// Fused GEMM + attention logits + bf16 pack.
// h = A@W (fp32 accum). Emits: h_bf (bf16, packed 2/uint), als, ald.
// Thread t: rows m0..m0+3 (m0=(t>>4)*4), cols 8*cg..8*cg+7 (cg=t&15).
// ------------------------------------------------------------------
__global__ __launch_bounds__(256) void k_gemm_al(const float* __restrict__ A,
                                                 const float* __restrict__ W,
                                                 const float* __restrict__ a_src,
                                                 const float* __restrict__ a_dst,
                                                 unsigned* __restrict__ h_bf,
                                                 float* __restrict__ als,
                                                 float* __restrict__ ald, int M) {
    __shared__ float Xt[128][64];  // [k][m] 32 KB
    int t = threadIdx.x;
    int mbase = blockIdx.x * 64;
    {
        int r = t & 63;
        int row = mbase + r;
        if (row >= M) row = 0;  // clamp; stores are guarded
        const float4* A4 = (const float4*)A;
#pragma unroll
        for (int j = 0; j < 8; ++j) {
            int k4 = (t >> 6) + j * 4;
            float4 v = A4[(size_t)row * 32 + k4];
            int kf = k4 * 4;
            Xt[kf + 0][r] = v.x;
            Xt[kf + 1][r] = v.y;
            Xt[kf + 2][r] = v.z;
            Xt[kf + 3][r] = v.w;
        }
    }
    __syncthreads();
    int m0 = (t >> 4) * 4;
    int cg = t & 15;          // col-group: cols 8cg..8cg+7
    int n4 = cg * 2;          // float4 col index
    float acc[4][8];
#pragma unroll
    for (int i = 0; i < 4; ++i)
#pragma unroll
        for (int j = 0; j < 8; ++j) acc[i][j] = 0.f;
    const float4* W4 = (const float4*)W;
#pragma unroll 4
    for (int k = 0; k < 128; ++k) {
        float4 b0 = W4[k * 32 + n4];
        float4 b1 = W4[k * 32 + n4 + 1];
        float4 a = *(const float4*)&Xt[k][m0];
        float av[4] = {a.x, a.y, a.z, a.w};
        float bv[8] = {b0.x, b0.y, b0.z, b0.w, b1.x, b1.y, b1.z, b1.w};
#pragma unroll
        for (int i = 0; i < 4; ++i)
#pragma unroll
            for (int j = 0; j < 8; ++j) acc[i][j] += av[i] * bv[j];
    }
    // epilogue: bf16 pack + per-head attention logits
    int head  = cg >> 1;
    int half8 = (cg & 1) * 8;
    const float4* asp = (const float4*)(a_src + head * 16 + half8);
    const float4* adp = (const float4*)(a_dst + head * 16 + half8);
    float4 as0 = asp[0], as1 = asp[1];
    float4 ad0 = adp[0], ad1 = adp[1];
    uint4* hb4 = (uint4*)h_bf;
#pragma unroll
    for (int i = 0; i < 4; ++i) {
        int m = mbase + m0 + i;
        float* a8 = acc[i];
        float ps = a8[0]*as0.x + a8[1]*as0.y + a8[2]*as0.z + a8[3]*as0.w
                 + a8[4]*as1.x + a8[5]*as1.y + a8[6]*as1.z + a8[7]*as1.w;
        float pd = a8[0]*ad0.x + a8[1]*ad0.y + a8[2]*ad0.z + a8[3]*ad0.w
                 + a8[4]*ad1.x + a8[5]*ad1.y + a8[6]*ad1.z + a8[7]*ad1.w;
        ps += __shfl_xor(ps, 1, 64);
        pd += __shfl_xor(pd, 1, 64);
        if (m < M) {
            uint4 hb;
            hb.x = bf16rne(a8[0]) | (bf16rne(a8[1]) << 16);
            hb.y = bf16rne(a8[2]) | (bf16rne(a8[3]) << 16);
            hb.z = bf16rne(a8[4]) | (bf16rne(a8[5]) << 16);
            hb.w = bf16rne(a8[6]) | (bf16rne(a8[7]) << 16);
            hb4[(size_t)m * 16 + cg] = hb;
            if ((cg & 1) == 0) {
                als[(size_t)m * 8 + head] = ps;
                ald[(size_t)m * 8 + head] = pd;
            }
        }
    }
}

// ------------------------------------------------------------------
// Segment softmax stats, head-per-lane (8 nodes x 8 heads per wave).
// Uses monotonicity: max(leaky(as+ad)) = leaky(max(as)+ad).
// ------------------------------------------------------------------
__global__ __launch_bounds__(256) void k_ms(const float* __restrict__ als,
                                            const float* __restrict__ ald,
                                            const int* __restrict__ rowptr,
                                            const int* __restrict__ ssrc,
                                            float* __restrict__ mbuf,
                                            float* __restrict__ isbuf, int n) {
    int wid  = (blockIdx.x * blockDim.x + threadIdx.x) >> 6;
    int lane = threadIdx.x & 63;
    int g = lane >> 3, hh = lane & 7;
    int node = wid * 8 + g;
    bool act = node < n;
    int nc = act ? node : 0;
    int start = rowptr[nc];
    int end   = rowptr[nc + 1];
    float av  = ald[(size_t)nc * 8 + hh];

    float mv = -1e30f, mv2 = -1e30f;
    int e = start;
    for (; e + 1 < end; e += 2) {
        mv  = fmaxf(mv,  als[(size_t)ssrc[e]     * 8 + hh]);
        mv2 = fmaxf(mv2, als[(size_t)ssrc[e + 1] * 8 + hh]);
    }
    if (e < end) mv = fmaxf(mv, als[(size_t)ssrc[e] * 8 + hh]);
    float mm = fmaxf(mv, mv2) + av;
    mm = mm >= 0.f ? mm : 0.2f * mm;

    float s = 0.f, s2 = 0.f;
    e = start;
    for (; e + 1 < end; e += 2) {
        float x1 = als[(size_t)ssrc[e]     * 8 + hh] + av;
        float x2 = als[(size_t)ssrc[e + 1] * 8 + hh] + av;
        float e1 = x1 >= 0.f ? x1 : 0.2f * x1;
        float e2 = x2 >= 0.f ? x2 : 0.2f * x2;
        s  += __expf(e1 - mm);
        s2 += __expf(e2 - mm);
    }
    if (e < end) {
        float x1 = als[(size_t)ssrc[e] * 8 + hh] + av;
        float e1 = x1 >= 0.f ? x1 : 0.2f * x1;
        s += __expf(e1 - mm);
    }
    if (act) {
        mbuf[(size_t)node * 8 + hh]  = mm;
        isbuf[(size_t)node * 8 + hh] = 1.0f / (s + s2 + 1e-16f);
    }
}

// ------------------------------------------------------------------
// Weighted aggregation over bf16 h. One wave per dst node; quarter-wave
// (16 lanes) per edge -> 4 edges concurrent, unrolled 2x (8 in flight).
// Lane q=lane&15 covers cols 8q..8q+7 (head q>>1), 16 B/lane gather.
// ------------------------------------------------------------------
__global__ __launch_bounds__(256) void k_agg(const unsigned* __restrict__ h_bf,
                                             const float* __restrict__ als,
                                             const float* __restrict__ ald,
                                             const float* __restrict__ mbuf,
                                             const float* __restrict__ isbuf,
                                             const int* __restrict__ rowptr,
                                             const int* __restrict__ ssrc,
                                             const float* __restrict__ bias,
                                             float* __restrict__ out,
                                             int n, int do_relu) {
    int wid  = (blockIdx.x * blockDim.x + threadIdx.x) >> 6;
    int lane = threadIdx.x & 63;
    if (wid >= n) return;
    int start = rowptr[wid];
    int end   = rowptr[wid + 1];
    int sub = lane >> 4;   // edge slot 0..3
    int q   = lane & 15;   // col-octet, cols 8q..8q+7
    int hd  = q >> 1;

    float mh  = mbuf[(size_t)wid * 8 + hd];
    float ish = isbuf[(size_t)wid * 8 + hd];
    float ah  = ald[(size_t)wid * 8 + hd];

    float acc[8];
#pragma unroll
    for (int j = 0; j < 8; ++j) acc[j] = 0.f;

    const uint4* h16 = (const uint4*)h_bf;
    for (int e0 = start; e0 < end; e0 += 8) {
        int ea = e0 + sub;
        int eb = e0 + 4 + sub;
        bool va = ea < end, vb = eb < end;
        int sa = ssrc[va ? ea : start];
        int sb = ssrc[vb ? eb : start];
        uint4 ra = h16[(size_t)sa * 16 + q];
        uint4 rb = h16[(size_t)sb * 16 + q];
        float xa = als[(size_t)sa * 8 + hd] + ah;
        float xb = als[(size_t)sb * 8 + hd] + ah;
        float ela = xa >= 0.f ? xa : 0.2f * xa;
        float elb = xb >= 0.f ? xb : 0.2f * xb;
        float wa = va ? __expf(ela - mh) : 0.f;
        float wb = vb ? __expf(elb - mh) : 0.f;
#define ULO(u) __uint_as_float((u) << 16)
#define UHI(u) __uint_as_float((u) & 0xffff0000u)
        acc[0] += wa * ULO(ra.x); acc[1] += wa * UHI(ra.x);
        acc[2] += wa * ULO(ra.y); acc[3] += wa * UHI(ra.y);
        acc[4] += wa * ULO(ra.z); acc[5] += wa * UHI(ra.z);
        acc[6] += wa * ULO(ra.w); acc[7] += wa * UHI(ra.w);
        acc[0] += wb * ULO(rb.x); acc[1] += wb * UHI(rb.x);
        acc[2] += wb * ULO(rb.y); acc[3] += wb * UHI(rb.y);
        acc[4] += wb * ULO(rb.z); acc[5] += wb * UHI(rb.z);
        acc[6] += wb * ULO(rb.w); acc[7] += wb * UHI(rb.w);
#undef ULO
#undef UHI
    }
    // sum across the 4 edge slots (lane bits 4,5)
#pragma unroll
    for (int j = 0; j < 8; ++j) {
        acc[j] += __shfl_xor(acc[j], 16, 64);
        acc[j] += __shfl_xor(acc[j], 32, 64);
    }
    if (lane < 16) {
        const float4* b4 = (const float4*)bias;
        float4 bl = b4[q * 2], bh = b4[q * 2 + 1];
        float4 o0 = {acc[0] * ish + bl.x, acc[1] * ish + bl.y,
                     acc[2] * ish + bl.z, acc[3] * ish + bl.w};
        float4 o1 = {acc[4] * ish + bh.x, acc[5] * ish + bh.y,
                     acc[6] * ish + bh.z, acc[7] * ish + bh.w};
        if (do_relu) {
            o0.x = fmaxf(o0.x, 0.f); o0.y = fmaxf(o0.y, 0.f);
            o0.z = fmaxf(o0.z, 0.f); o0.w = fmaxf(o0.w, 0.f);
            o1.x = fmaxf(o1.x, 0.f); o1.y = fmaxf(o1.y, 0.f);
            o1.z = fmaxf(o1.z, 0.f); o1.w = fmaxf(o1.w, 0.f);
        }
        float4* o4 = (float4*)out;
        o4[(size_t)wid * 32 + q * 2]     = o0;
        o4[(size_t)wid * 32 + q * 2 + 1] = o1;
    }
}

// ------------------------------------------------------------------
// Prediction heads
// ------------------------------------------------------------------
__global__ __launch_bounds__(256) void k_heads(const float* __restrict__ z,
                                               const int* __restrict__ tidx,
                                               const int* __restrict__ cidx,
                                               const float* __restrict__ wy1,
                                               const float* __restrict__ by1,
                                               const float* __restrict__ wy0,
                                               const float* __restrict__ by0,
                                               float* __restrict__ out, int M) {
    int wid  = (blockIdx.x * blockDim.x + threadIdx.x) >> 6;
    int lane = threadIdx.x & 63;
    if (wid >= 2 * M) return;
    int which = (wid >= M) ? 1 : 0;
    int i = wid - which * M;
    int idx = which ? cidx[i] : tidx[i];
    float2 zv = ((const float2*)(z + (size_t)idx * 128))[lane];
    float2 w1 = ((const float2*)wy1)[lane];
    float2 w0 = ((const float2*)wy0)[lane];
    float d1 = zv.x * w1.x + zv.y * w1.y;
    float d0 = zv.x * w0.x + zv.y * w0.y;
#pragma unroll
    for (int off = 32; off > 0; off >>= 1) {
        d1 += __shfl_xor(d1, off, 64);
        d0 += __shfl_xor(d0, off, 64);
    }
    if (lane == 0) {
        float y1v = d1 + by1[0]; y1v = y1v >= 0.f ? y1v : 0.01f * y1v;
        float y0v = d0 + by0[0]; y0v = y0v >= 0.f ? y0v : 0.01f * y0v;
        if (which == 0) { out[i] = y1v; out[M + i] = y0v; }
        else            { out[2 * M + i] = y0v; out[3 * M + i] = y1v; }
    }
}

// ------------------------------------------------------------------
extern "C" void kernel_launch(void* const* d_in, const int* in_sizes, int n_in,
                              void* d_out, int out_size, void* d_ws, size_t ws_size,
                              hipStream_t stream) {
    const float* x   = (const float*)d_in[0];
    const int*   ei  = (const int*)d_in[1];
    const int*   tix = (const int*)d_in[2];
    const int*   cix = (const int*)d_in[3];
    const float* W1  = (const float*)d_in[4];
    const float* as1 = (const float*)d_in[5];
    const float* ad1 = (const float*)d_in[6];
    const float* b1  = (const float*)d_in[7];
    const float* W2  = (const float*)d_in[8];
    const float* as2 = (const float*)d_in[9];
    const float* ad2 = (const float*)d_in[10];
    const float* b2  = (const float*)d_in[11];
    const float* wy1 = (const float*)d_in[12];
    const float* by1 = (const float*)d_in[13];
    const float* wy0 = (const float*)d_in[14];
    const float* by0 = (const float*)d_in[15];
    float* out = (float*)d_out;

    // workspace layout
    float* z_buf    = (float*)d_ws;             // 12.8M f (xZ1)
    unsigned* h_bf  = (unsigned*)(z_buf + 12800000); // 6.4M u (bf16 h, packed)
    float* als      = (float*)(h_bf + 6400000); // 800k f
    float* ald      = als + 800000;             // 800k f
    float* mbuf     = ald + 800000;             // 800k f
    float* isbuf    = mbuf + 800000;            // 800k f
    int* deg        = (int*)(isbuf + 800000);   // 100001
    int* rowptr     = deg + 100001;             // 100001
    int* cursor     = rowptr + 100001;          // 100001
    int* parts      = cursor + 100001;          // 512
    int* ssrc       = parts + 512;              // 1.7M

    dim3 B(256);
    // ---- CSR build ----
    k_init<<<(N_NODESC + 255) / 256, B, 0, stream>>>(deg, rowptr);
    k_hist<<<(N_EDGESC + 255) / 256, B, 0, stream>>>(ei, deg);
    k_scanA<<<NB_SCAN, B, 0, stream>>>(deg, parts);
    k_scanB<<<1, dim3(512), 0, stream>>>(parts);
    k_scanC<<<NB_SCAN, B, 0, stream>>>(deg, parts, rowptr, cursor);
    k_scatter<<<(E_TOTC + 255) / 256, B, 0, stream>>>(ei, cursor, ssrc);
    // ---- layer 1 ----
    k_gemm_al<<<(N_NODESC + 63) / 64, B, 0, stream>>>(x, W1, as1, ad1, h_bf, als, ald, N_NODESC);
    k_ms<<<(N_NODESC + 31) / 32, B, 0, stream>>>(als, ald, rowptr, ssrc, mbuf, isbuf, N_NODESC);
    k_agg<<<(N_NODESC + 3) / 4, B, 0, stream>>>(h_bf, als, ald, mbuf, isbuf, rowptr, ssrc,
                                                b1, z_buf, N_NODESC, 1);
    // ---- layer 2 ----
    k_gemm_al<<<(N_NODESC + 63) / 64, B, 0, stream>>>(z_buf, W2, as2, ad2, h_bf, als, ald, N_NODESC);
    k_ms<<<(N_NODESC + 31) / 32, B, 0, stream>>>(als, ald, rowptr, ssrc, mbuf, isbuf, N_NODESC);
    k_agg<<<(N_NODESC + 3) / 4, B, 0, stream>>>(h_bf, als, ald, mbuf, isbuf, rowptr, ssrc,
                                                b2, out + 80000, N_NODESC, 0);
    // ---- heads ----
    k_heads<<<(2 * 20000 * 64) / 256, B, 0, stream>>>(out + 80000, tix, cix,
                                                      wy1, by1, wy0, by0, out, 20000);
}

// Round 4
// 615.936 us; speedup vs baseline: 1.4471x; 1.1338x over previous
//
#include <hip/hip_runtime.h>

#define N_NODESC 100000
#define N_EDGESC 1600000
#define E_TOTC   1700000
#define NB_SCAN  391   // ceil(100000/256)
#define NBK      391   // dst buckets of 256 nodes
#define EPB      4096  // edges per k_bucket block
#define NBA      416   // ceil(E_TOTC/EPB)

__device__ inline unsigned bf16rne(float x) {
    unsigned u = __float_as_uint(x);
    return (u + 0x7fffu + ((u >> 16) & 1u)) >> 16;
}

// ------------------------------------------------------------------
// CSR build (grouped by dst) of edge list + self loops
// ------------------------------------------------------------------
__global__ void k_init(int* deg, int* rowptr) {
    int i = blockIdx.x * 256 + threadIdx.x;
    if (i < N_NODESC) deg[i] = 1;             // self-loop contributes 1
    if (i == 0) rowptr[N_NODESC] = E_TOTC;
}

__global__ void k_hist(const int* __restrict__ ei, int* deg) {
    int e = blockIdx.x * 256 + threadIdx.x;
    if (e < N_EDGESC) atomicAdd(&deg[ei[N_EDGESC + e]], 1);
}

__global__ void k_scanA(const int* __restrict__ deg, int* partials) {
    __shared__ int sd[256];
    int t = threadIdx.x;
    int i = blockIdx.x * 256 + t;
    sd[t] = (i < N_NODESC) ? deg[i] : 0;
    __syncthreads();
    for (int off = 128; off > 0; off >>= 1) {
        if (t < off) sd[t] += sd[t + off];
        __syncthreads();
    }
    if (t == 0) partials[blockIdx.x] = sd[0];
}

__global__ void k_scanB(int* partials) {
    __shared__ int sd[512];
    int t = threadIdx.x;
    int v = (t < NB_SCAN) ? partials[t] : 0;
    sd[t] = v;
    __syncthreads();
    for (int off = 1; off < 512; off <<= 1) {
        int x = (t >= off) ? sd[t - off] : 0;
        __syncthreads();
        sd[t] += x;
        __syncthreads();
    }
    if (t < NB_SCAN) partials[t] = sd[t] - v;  // exclusive scan of block sums
}

__global__ void k_scanC(const int* __restrict__ deg, const int* __restrict__ partials,
                        int* rowptr, int* gcur) {
    __shared__ int sd[256];
    int t = threadIdx.x;
    int i = blockIdx.x * 256 + t;
    int v = (i < N_NODESC) ? deg[i] : 0;
    sd[t] = v;
    __syncthreads();
    for (int off = 1; off < 256; off <<= 1) {
        int x = (t >= off) ? sd[t - off] : 0;
        __syncthreads();
        sd[t] += x;
        __syncthreads();
    }
    int excl = sd[t] - v + partials[blockIdx.x];
    if (i < N_NODESC) {
        rowptr[i] = excl;
        if ((i & 255) == 0) gcur[i >> 8] = excl;  // bucket write cursor
    }
}

// ------------------------------------------------------------------
// Phase A: bucket edges by dst>>8 into tmp (same layout as final ssrc).
// Block-aggregated chunk reservation -> near-contiguous writes.
// Payload: s | (dlocal<<20), dlocal = d & 255.
// ------------------------------------------------------------------
__global__ __launch_bounds__(256) void k_bucket(const int* __restrict__ ei,
                                                int* gcur, unsigned* __restrict__ tmp) {
    __shared__ int hist[NBK];
    __shared__ int cnt[NBK];
    __shared__ int base[NBK];
    int t = threadIdx.x;
    for (int i = t; i < NBK; i += 256) { hist[i] = 0; cnt[i] = 0; }
    __syncthreads();

    int e0 = blockIdx.x * EPB;
    int ss[16], dd[16];
#pragma unroll
    for (int j = 0; j < 16; ++j) {
        int e = e0 + j * 256 + t;
        if (e < E_TOTC) {
            if (e < N_EDGESC) { ss[j] = ei[e]; dd[j] = ei[N_EDGESC + e]; }
            else { ss[j] = dd[j] = e - N_EDGESC; }
            atomicAdd(&hist[dd[j] >> 8], 1);
        } else {
            dd[j] = -1;
        }
    }
    __syncthreads();
    for (int i = t; i < NBK; i += 256) {
        int c = hist[i];
        base[i] = c > 0 ? atomicAdd(&gcur[i], c) : 0;
    }
    __syncthreads();
#pragma unroll
    for (int j = 0; j < 16; ++j) {
        if (dd[j] >= 0) {
            int b = dd[j] >> 8;
            int pos = base[b] + atomicAdd(&cnt[b], 1);
            tmp[pos] = (unsigned)ss[j] | ((unsigned)(dd[j] & 255) << 20);
        }
    }
}

// ------------------------------------------------------------------
// Phase B: one block per bucket; LDS per-node cursors; writes confined
// to the bucket's contiguous ssrc window.
// ------------------------------------------------------------------
__global__ __launch_bounds__(256) void k_place(const unsigned* __restrict__ tmp,
                                               const int* __restrict__ rowptr,
                                               int* __restrict__ ssrc) {
    __shared__ int lcur[256];
    int b = blockIdx.x;
    int t = threadIdx.x;
    int node0 = b * 256;
    int nd = node0 + t;
    lcur[t] = (nd < N_NODESC) ? rowptr[nd] : E_TOTC;
    int hi = node0 + 256;
    if (hi > N_NODESC) hi = N_NODESC;
    int rbeg = rowptr[node0];
    int rend = rowptr[hi];
    __syncthreads();
    for (int e = rbeg + t; e < rend; e += 256) {
        unsigned p = tmp[e];
        int dl = p >> 20;
        int s  = p & 0xFFFFFu;
        int pos = atomicAdd(&lcur[dl], 1);
        ssrc[pos] = s;
    }
}

// ------------------------------------------------------------------
// Fused GEMM + attention logits + bf16 pack.
// ------------------------------------------------------------------
__global__ __launch_bounds__(256) void k_gemm_al(const float* __restrict__ A,
                                                 const float* __restrict__ W,
                                                 const float* __restrict__ a_src,
                                                 const float* __restrict__ a_dst,
                                                 unsigned* __restrict__ h_bf,
                                                 float* __restrict__ als,
                                                 float* __restrict__ ald, int M) {
    __shared__ float Xt[128][64];  // [k][m] 32 KB
    int t = threadIdx.x;
    int mbase = blockIdx.x * 64;
    {
        int r = t & 63;
        int row = mbase + r;
        if (row >= M) row = 0;  // clamp; stores are guarded
        const float4* A4 = (const float4*)A;
#pragma unroll
        for (int j = 0; j < 8; ++j) {
            int k4 = (t >> 6) + j * 4;
            float4 v = A4[(size_t)row * 32 + k4];
            int kf = k4 * 4;
            Xt[kf + 0][r] = v.x;
            Xt[kf + 1][r] = v.y;
            Xt[kf + 2][r] = v.z;
            Xt[kf + 3][r] = v.w;
        }
    }
    __syncthreads();
    int m0 = (t >> 4) * 4;
    int cg = t & 15;          // col-group: cols 8cg..8cg+7
    int n4 = cg * 2;
    float acc[4][8];
#pragma unroll
    for (int i = 0; i < 4; ++i)
#pragma unroll
        for (int j = 0; j < 8; ++j) acc[i][j] = 0.f;
    const float4* W4 = (const float4*)W;
#pragma unroll 4
    for (int k = 0; k < 128; ++k) {
        float4 b0 = W4[k * 32 + n4];
        float4 b1 = W4[k * 32 + n4 + 1];
        float4 a = *(const float4*)&Xt[k][m0];
        float av[4] = {a.x, a.y, a.z, a.w};
        float bv[8] = {b0.x, b0.y, b0.z, b0.w, b1.x, b1.y, b1.z, b1.w};
#pragma unroll
        for (int i = 0; i < 4; ++i)
#pragma unroll
            for (int j = 0; j < 8; ++j) acc[i][j] += av[i] * bv[j];
    }
    // epilogue: bf16 pack + per-head attention logits
    int head  = cg >> 1;
    int half8 = (cg & 1) * 8;
    const float4* asp = (const float4*)(a_src + head * 16 + half8);
    const float4* adp = (const float4*)(a_dst + head * 16 + half8);
    float4 as0 = asp[0], as1 = asp[1];
    float4 ad0 = adp[0], ad1 = adp[1];
    uint4* hb4 = (uint4*)h_bf;
#pragma unroll
    for (int i = 0; i < 4; ++i) {
        int m = mbase + m0 + i;
        float* a8 = acc[i];
        float ps = a8[0]*as0.x + a8[1]*as0.y + a8[2]*as0.z + a8[3]*as0.w
                 + a8[4]*as1.x + a8[5]*as1.y + a8[6]*as1.z + a8[7]*as1.w;
        float pd = a8[0]*ad0.x + a8[1]*ad0.y + a8[2]*ad0.z + a8[3]*ad0.w
                 + a8[4]*ad1.x + a8[5]*ad1.y + a8[6]*ad1.z + a8[7]*ad1.w;
        ps += __shfl_xor(ps, 1, 64);
        pd += __shfl_xor(pd, 1, 64);
        if (m < M) {
            uint4 hb;
            hb.x = bf16rne(a8[0]) | (bf16rne(a8[1]) << 16);
            hb.y = bf16rne(a8[2]) | (bf16rne(a8[3]) << 16);
            hb.z = bf16rne(a8[4]) | (bf16rne(a8[5]) << 16);
            hb.w = bf16rne(a8[6]) | (bf16rne(a8[7]) << 16);
            hb4[(size_t)m * 16 + cg] = hb;
            if ((cg & 1) == 0) {
                als[(size_t)m * 8 + head] = ps;
                ald[(size_t)m * 8 + head] = pd;
            }
        }
    }
}

// ------------------------------------------------------------------
// Segment softmax stats, head-per-lane (8 nodes x 8 heads per wave).
// ------------------------------------------------------------------
__global__ __launch_bounds__(256) void k_ms(const float* __restrict__ als,
                                            const float* __restrict__ ald,
                                            const int* __restrict__ rowptr,
                                            const int* __restrict__ ssrc,
                                            float* __restrict__ mbuf,
                                            float* __restrict__ isbuf, int n) {
    int wid  = (blockIdx.x * blockDim.x + threadIdx.x) >> 6;
    int lane = threadIdx.x & 63;
    int g = lane >> 3, hh = lane & 7;
    int node = wid * 8 + g;
    bool act = node < n;
    int nc = act ? node : 0;
    int start = rowptr[nc];
    int end   = rowptr[nc + 1];
    float av  = ald[(size_t)nc * 8 + hh];

    float mv = -1e30f, mv2 = -1e30f;
    int e = start;
    for (; e + 1 < end; e += 2) {
        mv  = fmaxf(mv,  als[(size_t)ssrc[e]     * 8 + hh]);
        mv2 = fmaxf(mv2, als[(size_t)ssrc[e + 1] * 8 + hh]);
    }
    if (e < end) mv = fmaxf(mv, als[(size_t)ssrc[e] * 8 + hh]);
    float mm = fmaxf(mv, mv2) + av;
    mm = mm >= 0.f ? mm : 0.2f * mm;

    float s = 0.f, s2 = 0.f;
    e = start;
    for (; e + 1 < end; e += 2) {
        float x1 = als[(size_t)ssrc[e]     * 8 + hh] + av;
        float x2 = als[(size_t)ssrc[e + 1] * 8 + hh] + av;
        float e1 = x1 >= 0.f ? x1 : 0.2f * x1;
        float e2 = x2 >= 0.f ? x2 : 0.2f * x2;
        s  += __expf(e1 - mm);
        s2 += __expf(e2 - mm);
    }
    if (e < end) {
        float x1 = als[(size_t)ssrc[e] * 8 + hh] + av;
        float e1 = x1 >= 0.f ? x1 : 0.2f * x1;
        s += __expf(e1 - mm);
    }
    if (act) {
        mbuf[(size_t)node * 8 + hh]  = mm;
        isbuf[(size_t)node * 8 + hh] = 1.0f / (s + s2 + 1e-16f);
    }
}

// ------------------------------------------------------------------
// Weighted aggregation over bf16 h. One wave per dst node; quarter-wave
// (16 lanes) per edge -> 4 edges concurrent, unrolled 2x.
// ------------------------------------------------------------------
__global__ __launch_bounds__(256) void k_agg(const unsigned* __restrict__ h_bf,
                                             const float* __restrict__ als,
                                             const float* __restrict__ ald,
                                             const float* __restrict__ mbuf,
                                             const float* __restrict__ isbuf,
                                             const int* __restrict__ rowptr,
                                             const int* __restrict__ ssrc,
                                             const float* __restrict__ bias,
                                             float* __restrict__ out,
                                             int n, int do_relu) {
    int wid  = (blockIdx.x * blockDim.x + threadIdx.x) >> 6;
    int lane = threadIdx.x & 63;
    if (wid >= n) return;
    int start = rowptr[wid];
    int end   = rowptr[wid + 1];
    int sub = lane >> 4;   // edge slot 0..3
    int q   = lane & 15;   // col-octet, cols 8q..8q+7
    int hd  = q >> 1;

    float mh  = mbuf[(size_t)wid * 8 + hd];
    float ish = isbuf[(size_t)wid * 8 + hd];
    float ah  = ald[(size_t)wid * 8 + hd];

    float acc[8];
#pragma unroll
    for (int j = 0; j < 8; ++j) acc[j] = 0.f;

    const uint4* h16 = (const uint4*)h_bf;
    for (int e0 = start; e0 < end; e0 += 8) {
        int ea = e0 + sub;
        int eb = e0 + 4 + sub;
        bool va = ea < end, vb = eb < end;
        int sa = ssrc[va ? ea : start];
        int sb = ssrc[vb ? eb : start];
        uint4 ra = h16[(size_t)sa * 16 + q];
        uint4 rb = h16[(size_t)sb * 16 + q];
        float xa = als[(size_t)sa * 8 + hd] + ah;
        float xb = als[(size_t)sb * 8 + hd] + ah;
        float ela = xa >= 0.f ? xa : 0.2f * xa;
        float elb = xb >= 0.f ? xb : 0.2f * xb;
        float wa = va ? __expf(ela - mh) : 0.f;
        float wb = vb ? __expf(elb - mh) : 0.f;
#define ULO(u) __uint_as_float((u) << 16)
#define UHI(u) __uint_as_float((u) & 0xffff0000u)
        acc[0] += wa * ULO(ra.x); acc[1] += wa * UHI(ra.x);
        acc[2] += wa * ULO(ra.y); acc[3] += wa * UHI(ra.y);
        acc[4] += wa * ULO(ra.z); acc[5] += wa * UHI(ra.z);
        acc[6] += wa * ULO(ra.w); acc[7] += wa * UHI(ra.w);
        acc[0] += wb * ULO(rb.x); acc[1] += wb * UHI(rb.x);
        acc[2] += wb * ULO(rb.y); acc[3] += wb * UHI(rb.y);
        acc[4] += wb * ULO(rb.z); acc[5] += wb * UHI(rb.z);
        acc[6] += wb * ULO(rb.w); acc[7] += wb * UHI(rb.w);
#undef ULO
#undef UHI
    }
#pragma unroll
    for (int j = 0; j < 8; ++j) {
        acc[j] += __shfl_xor(acc[j], 16, 64);
        acc[j] += __shfl_xor(acc[j], 32, 64);
    }
    if (lane < 16) {
        const float4* b4 = (const float4*)bias;
        float4 bl = b4[q * 2], bh = b4[q * 2 + 1];
        float4 o0 = {acc[0] * ish + bl.x, acc[1] * ish + bl.y,
                     acc[2] * ish + bl.z, acc[3] * ish + bl.w};
        float4 o1 = {acc[4] * ish + bh.x, acc[5] * ish + bh.y,
                     acc[6] * ish + bh.z, acc[7] * ish + bh.w};
        if (do_relu) {
            o0.x = fmaxf(o0.x, 0.f); o0.y = fmaxf(o0.y, 0.f);
            o0.z = fmaxf(o0.z, 0.f); o0.w = fmaxf(o0.w, 0.f);
            o1.x = fmaxf(o1.x, 0.f); o1.y = fmaxf(o1.y, 0.f);
            o1.z = fmaxf(o1.z, 0.f); o1.w = fmaxf(o1.w, 0.f);
        }
        float4* o4 = (float4*)out;
        o4[(size_t)wid * 32 + q * 2]     = o0;
        o4[(size_t)wid * 32 + q * 2 + 1] = o1;
    }
}

// ------------------------------------------------------------------
// Prediction heads
// ------------------------------------------------------------------
__global__ __launch_bounds__(256) void k_heads(const float* __restrict__ z,
                                               const int* __restrict__ tidx,
                                               const int* __restrict__ cidx,
                                               const float* __restrict__ wy1,
                                               const float* __restrict__ by1,
                                               const float* __restrict__ wy0,
                                               const float* __restrict__ by0,
                                               float* __restrict__ out, int M) {
    int wid  = (blockIdx.x * blockDim.x + threadIdx.x) >> 6;
    int lane = threadIdx.x & 63;
    if (wid >= 2 * M) return;
    int which = (wid >= M) ? 1 : 0;
    int i = wid - which * M;
    int idx = which ? cidx[i] : tidx[i];
    float2 zv = ((const float2*)(z + (size_t)idx * 128))[lane];
    float2 w1 = ((const float2*)wy1)[lane];
    float2 w0 = ((const float2*)wy0)[lane];
    float d1 = zv.x * w1.x + zv.y * w1.y;
    float d0 = zv.x * w0.x + zv.y * w0.y;
#pragma unroll
    for (int off = 32; off > 0; off >>= 1) {
        d1 += __shfl_xor(d1, off, 64);
        d0 += __shfl_xor(d0, off, 64);
    }
    if (lane == 0) {
        float y1v = d1 + by1[0]; y1v = y1v >= 0.f ? y1v : 0.01f * y1v;
        float y0v = d0 + by0[0]; y0v = y0v >= 0.f ? y0v : 0.01f * y0v;
        if (which == 0) { out[i] = y1v; out[M + i] = y0v; }
        else            { out[2 * M + i] = y0v; out[3 * M + i] = y1v; }
    }
}

// ------------------------------------------------------------------
extern "C" void kernel_launch(void* const* d_in, const int* in_sizes, int n_in,
                              void* d_out, int out_size, void* d_ws, size_t ws_size,
                              hipStream_t stream) {
    const float* x   = (const float*)d_in[0];
    const int*   ei  = (const int*)d_in[1];
    const int*   tix = (const int*)d_in[2];
    const int*   cix = (const int*)d_in[3];
    const float* W1  = (const float*)d_in[4];
    const float* as1 = (const float*)d_in[5];
    const float* ad1 = (const float*)d_in[6];
    const float* b1  = (const float*)d_in[7];
    const float* W2  = (const float*)d_in[8];
    const float* as2 = (const float*)d_in[9];
    const float* ad2 = (const float*)d_in[10];
    const float* b2  = (const float*)d_in[11];
    const float* wy1 = (const float*)d_in[12];
    const float* by1 = (const float*)d_in[13];
    const float* wy0 = (const float*)d_in[14];
    const float* by0 = (const float*)d_in[15];
    float* out = (float*)d_out;

    // workspace layout
    float* z_buf    = (float*)d_ws;                  // 12.8M f (xZ1)
    unsigned* h_bf  = (unsigned*)(z_buf + 12800000); // 6.4M u (bf16 h)
    float* als      = (float*)(h_bf + 6400000);      // 800k f
    float* ald      = als + 800000;                  // 800k f
    float* mbuf     = ald + 800000;                  // 800k f
    float* isbuf    = mbuf + 800000;                 // 800k f
    int* deg        = (int*)(isbuf + 800000);        // 100001
    int* rowptr     = deg + 100001;                  // 100001
    int* gcur       = rowptr + 100001;               // 512
    int* parts      = gcur + 512;                    // 512
    int* ssrc       = parts + 512;                   // 1.7M
    unsigned* tmp   = (unsigned*)(ssrc + E_TOTC);    // 1.7M

    dim3 B(256);
    // ---- CSR build ----
    k_init<<<(N_NODESC + 255) / 256, B, 0, stream>>>(deg, rowptr);
    k_hist<<<(N_EDGESC + 255) / 256, B, 0, stream>>>(ei, deg);
    k_scanA<<<NB_SCAN, B, 0, stream>>>(deg, parts);
    k_scanB<<<1, dim3(512), 0, stream>>>(parts);
    k_scanC<<<NB_SCAN, B, 0, stream>>>(deg, parts, rowptr, gcur);
    k_bucket<<<NBA, B, 0, stream>>>(ei, gcur, tmp);
    k_place<<<NBK, B, 0, stream>>>(tmp, rowptr, ssrc);
    // ---- layer 1 ----
    k_gemm_al<<<(N_NODESC + 63) / 64, B, 0, stream>>>(x, W1, as1, ad1, h_bf, als, ald, N_NODESC);
    k_ms<<<(N_NODESC + 31) / 32, B, 0, stream>>>(als, ald, rowptr, ssrc, mbuf, isbuf, N_NODESC);
    k_agg<<<(N_NODESC + 3) / 4, B, 0, stream>>>(h_bf, als, ald, mbuf, isbuf, rowptr, ssrc,
                                                b1, z_buf, N_NODESC, 1);
    // ---- layer 2 ----
    k_gemm_al<<<(N_NODESC + 63) / 64, B, 0, stream>>>(z_buf, W2, as2, ad2, h_bf, als, ald, N_NODESC);
    k_ms<<<(N_NODESC + 31) / 32, B, 0, stream>>>(als, ald, rowptr, ssrc, mbuf, isbuf, N_NODESC);
    k_agg<<<(N_NODESC + 3) / 4, B, 0, stream>>>(h_bf, als, ald, mbuf, isbuf, rowptr, ssrc,
                                                b2, out + 80000, N_NODESC, 0);
    // ---- heads ----
    k_heads<<<(2 * 20000 * 64) / 256, B, 0, stream>>>(out + 80000, tix, cix,
                                                      wy1, by1, wy0, by0, out, 20000);
}

// Round 5
// 537.745 us; speedup vs baseline: 1.6575x; 1.1454x over previous
//
#include <hip/hip_runtime.h>

#define N_NODESC 100000
#define N_EDGESC 1600000
#define E_TOTC   1700000
#define NBK      391   // dst buckets of 256 nodes
#define EPB      4096  // edges per bucket-phase block
#define NBA      416   // ceil(E_TOTC/EPB)
#define NBC      391   // ceil(N_EDGESC/EPB)

__device__ inline unsigned bf16rne(float x) {
    unsigned u = __float_as_uint(x);
    return (u + 0x7fffu + ((u >> 16) & 1u)) >> 16;
}

// ------------------------------------------------------------------
// CSR build: bucket-count -> bucket-scan -> bucket-scatter -> place
// ------------------------------------------------------------------
__global__ void k_zero(int* bcnt, int* rowptr) {
    int i = blockIdx.x * 256 + threadIdx.x;
    if (i < NBK + 1) bcnt[i] = 0;
    if (i == 0) rowptr[N_NODESC] = E_TOTC;
}

// count real edges per dst-bucket (self-loops added as constants in k_bscan)
__global__ __launch_bounds__(256) void k_cnt(const int* __restrict__ ei, int* bcnt) {
    __shared__ int hist[NBK];
    int t = threadIdx.x;
    for (int i = t; i < NBK; i += 256) hist[i] = 0;
    __syncthreads();
    int e0 = blockIdx.x * EPB;
#pragma unroll
    for (int j = 0; j < 16; ++j) {
        int e = e0 + j * 256 + t;
        if (e < N_EDGESC) atomicAdd(&hist[ei[N_EDGESC + e] >> 8], 1);
    }
    __syncthreads();
    for (int i = t; i < NBK; i += 256) {
        int c = hist[i];
        if (c) atomicAdd(&bcnt[i], c);
    }
}

// exclusive scan of 391 bucket counts (+ per-bucket self-loop constants)
__global__ void k_bscan(const int* __restrict__ bcnt, int* bucketptr, int* gcur) {
    __shared__ int sd[512];
    int t = threadIdx.x;
    int v = 0;
    if (t < NBK) v = bcnt[t] + (t == NBK - 1 ? 160 : 256);  // self-loops per bucket
    sd[t] = v;
    __syncthreads();
    for (int off = 1; off < 512; off <<= 1) {
        int x = (t >= off) ? sd[t - off] : 0;
        __syncthreads();
        sd[t] += x;
        __syncthreads();
    }
    if (t <= NBK) {
        int excl = sd[t] - v;
        bucketptr[t] = excl;
        gcur[t] = excl;
    }
}

// Phase A: scatter edges (+self loops) into bucket-contiguous tmp.
// Payload: s | (dlocal<<20).
__global__ __launch_bounds__(256) void k_bucket(const int* __restrict__ ei,
                                                int* gcur, unsigned* __restrict__ tmp) {
    __shared__ int hist[NBK];
    __shared__ int cnt[NBK];
    __shared__ int base[NBK];
    int t = threadIdx.x;
    for (int i = t; i < NBK; i += 256) { hist[i] = 0; cnt[i] = 0; }
    __syncthreads();

    int e0 = blockIdx.x * EPB;
    int ss[16], dd[16];
#pragma unroll
    for (int j = 0; j < 16; ++j) {
        int e = e0 + j * 256 + t;
        if (e < E_TOTC) {
            if (e < N_EDGESC) { ss[j] = ei[e]; dd[j] = ei[N_EDGESC + e]; }
            else { ss[j] = dd[j] = e - N_EDGESC; }
            atomicAdd(&hist[dd[j] >> 8], 1);
        } else {
            dd[j] = -1;
        }
    }
    __syncthreads();
    for (int i = t; i < NBK; i += 256) {
        int c = hist[i];
        base[i] = c > 0 ? atomicAdd(&gcur[i], c) : 0;
    }
    __syncthreads();
#pragma unroll
    for (int j = 0; j < 16; ++j) {
        if (dd[j] >= 0) {
            int b = dd[j] >> 8;
            int pos = base[b] + atomicAdd(&cnt[b], 1);
            tmp[pos] = (unsigned)ss[j] | ((unsigned)(dd[j] & 255) << 20);
        }
    }
}

// Phase B: one block per bucket. Derives per-node degrees + rowptr from
// tmp (LDS count + scan), then places edges into the final ssrc window.
__global__ __launch_bounds__(256) void k_place(const unsigned* __restrict__ tmp,
                                               const int* __restrict__ bucketptr,
                                               int* __restrict__ rowptr,
                                               int* __restrict__ ssrc) {
    __shared__ int cnt256[256];
    __shared__ int sd[256];
    __shared__ int lcur[256];
    int b = blockIdx.x;
    int t = threadIdx.x;
    int rbeg = bucketptr[b];
    int rend = bucketptr[b + 1];
    cnt256[t] = 0;
    __syncthreads();
    for (int e = rbeg + t; e < rend; e += 256)
        atomicAdd(&cnt256[tmp[e] >> 20], 1);
    __syncthreads();
    int v = cnt256[t];
    sd[t] = v;
    __syncthreads();
    for (int off = 1; off < 256; off <<= 1) {
        int x = (t >= off) ? sd[t - off] : 0;
        __syncthreads();
        sd[t] += x;
        __syncthreads();
    }
    int rp = rbeg + sd[t] - v;   // exclusive
    int nd = b * 256 + t;
    if (nd < N_NODESC) rowptr[nd] = rp;
    lcur[t] = rp;
    __syncthreads();
    for (int e = rbeg + t; e < rend; e += 256) {
        unsigned p = tmp[e];
        int pos = atomicAdd(&lcur[p >> 20], 1);
        ssrc[pos] = p & 0xFFFFFu;
    }
}

// ------------------------------------------------------------------
// Fused GEMM + attention logits + bf16 pack.
// ------------------------------------------------------------------
__global__ __launch_bounds__(256) void k_gemm_al(const float* __restrict__ A,
                                                 const float* __restrict__ W,
                                                 const float* __restrict__ a_src,
                                                 const float* __restrict__ a_dst,
                                                 unsigned* __restrict__ h_bf,
                                                 float* __restrict__ als,
                                                 float* __restrict__ ald, int M) {
    __shared__ float Xt[128][64];  // [k][m] 32 KB
    int t = threadIdx.x;
    int mbase = blockIdx.x * 64;
    {
        int r = t & 63;
        int row = mbase + r;
        if (row >= M) row = 0;  // clamp; stores are guarded
        const float4* A4 = (const float4*)A;
#pragma unroll
        for (int j = 0; j < 8; ++j) {
            int k4 = (t >> 6) + j * 4;
            float4 v = A4[(size_t)row * 32 + k4];
            int kf = k4 * 4;
            Xt[kf + 0][r] = v.x;
            Xt[kf + 1][r] = v.y;
            Xt[kf + 2][r] = v.z;
            Xt[kf + 3][r] = v.w;
        }
    }
    __syncthreads();
    int m0 = (t >> 4) * 4;
    int cg = t & 15;          // col-group: cols 8cg..8cg+7
    int n4 = cg * 2;
    float acc[4][8];
#pragma unroll
    for (int i = 0; i < 4; ++i)
#pragma unroll
        for (int j = 0; j < 8; ++j) acc[i][j] = 0.f;
    const float4* W4 = (const float4*)W;
#pragma unroll 4
    for (int k = 0; k < 128; ++k) {
        float4 b0 = W4[k * 32 + n4];
        float4 b1 = W4[k * 32 + n4 + 1];
        float4 a = *(const float4*)&Xt[k][m0];
        float av[4] = {a.x, a.y, a.z, a.w};
        float bv[8] = {b0.x, b0.y, b0.z, b0.w, b1.x, b1.y, b1.z, b1.w};
#pragma unroll
        for (int i = 0; i < 4; ++i)
#pragma unroll
            for (int j = 0; j < 8; ++j) acc[i][j] += av[i] * bv[j];
    }
    // epilogue: bf16 pack + per-head attention logits
    int head  = cg >> 1;
    int half8 = (cg & 1) * 8;
    const float4* asp = (const float4*)(a_src + head * 16 + half8);
    const float4* adp = (const float4*)(a_dst + head * 16 + half8);
    float4 as0 = asp[0], as1 = asp[1];
    float4 ad0 = adp[0], ad1 = adp[1];
    uint4* hb4 = (uint4*)h_bf;
#pragma unroll
    for (int i = 0; i < 4; ++i) {
        int m = mbase + m0 + i;
        float* a8 = acc[i];
        float ps = a8[0]*as0.x + a8[1]*as0.y + a8[2]*as0.z + a8[3]*as0.w
                 + a8[4]*as1.x + a8[5]*as1.y + a8[6]*as1.z + a8[7]*as1.w;
        float pd = a8[0]*ad0.x + a8[1]*ad0.y + a8[2]*ad0.z + a8[3]*ad0.w
                 + a8[4]*ad1.x + a8[5]*ad1.y + a8[6]*ad1.z + a8[7]*ad1.w;
        ps += __shfl_xor(ps, 1, 64);
        pd += __shfl_xor(pd, 1, 64);
        if (m < M) {
            uint4 hb;
            hb.x = bf16rne(a8[0]) | (bf16rne(a8[1]) << 16);
            hb.y = bf16rne(a8[2]) | (bf16rne(a8[3]) << 16);
            hb.z = bf16rne(a8[4]) | (bf16rne(a8[5]) << 16);
            hb.w = bf16rne(a8[6]) | (bf16rne(a8[7]) << 16);
            hb4[(size_t)m * 16 + cg] = hb;
            if ((cg & 1) == 0) {
                als[(size_t)m * 8 + head] = ps;
                ald[(size_t)m * 8 + head] = pd;
            }
        }
    }
}

// ------------------------------------------------------------------
// Segment max ONLY (single pass), head-per-lane (8 nodes x 8 heads/wave).
// s is accumulated inside k_agg. Monotonicity: max(leaky(as+ad)) =
// leaky(max(as)+ad).
// ------------------------------------------------------------------
__global__ __launch_bounds__(256) void k_ms(const float* __restrict__ als,
                                            const float* __restrict__ ald,
                                            const int* __restrict__ rowptr,
                                            const int* __restrict__ ssrc,
                                            float* __restrict__ mbuf, int n) {
    int wid  = (blockIdx.x * blockDim.x + threadIdx.x) >> 6;
    int lane = threadIdx.x & 63;
    int g = lane >> 3, hh = lane & 7;
    int node = wid * 8 + g;
    bool act = node < n;
    int nc = act ? node : 0;
    int start = rowptr[nc];
    int end   = rowptr[nc + 1];
    float av  = ald[(size_t)nc * 8 + hh];

    float mv = -1e30f, mv2 = -1e30f;
    int e = start;
    for (; e + 1 < end; e += 2) {
        mv  = fmaxf(mv,  als[(size_t)ssrc[e]     * 8 + hh]);
        mv2 = fmaxf(mv2, als[(size_t)ssrc[e + 1] * 8 + hh]);
    }
    if (e < end) mv = fmaxf(mv, als[(size_t)ssrc[e] * 8 + hh]);
    float mm = fmaxf(mv, mv2) + av;
    mm = mm >= 0.f ? mm : 0.2f * mm;
    if (act) mbuf[(size_t)node * 8 + hh] = mm;
}

// ------------------------------------------------------------------
// Weighted aggregation over bf16 h + softmax denominator. One wave per
// dst node; quarter-wave per edge, 4 edges concurrent, 2x unroll.
// ------------------------------------------------------------------
__global__ __launch_bounds__(256) void k_agg(const unsigned* __restrict__ h_bf,
                                             const float* __restrict__ als,
                                             const float* __restrict__ ald,
                                             const float* __restrict__ mbuf,
                                             const int* __restrict__ rowptr,
                                             const int* __restrict__ ssrc,
                                             const float* __restrict__ bias,
                                             float* __restrict__ out,
                                             int n, int do_relu) {
    int wid  = (blockIdx.x * blockDim.x + threadIdx.x) >> 6;
    int lane = threadIdx.x & 63;
    if (wid >= n) return;
    int start = rowptr[wid];
    int end   = rowptr[wid + 1];
    int sub = lane >> 4;   // edge slot 0..3
    int q   = lane & 15;   // col-octet, cols 8q..8q+7
    int hd  = q >> 1;

    float mh = mbuf[(size_t)wid * 8 + hd];
    float ah = ald[(size_t)wid * 8 + hd];

    float acc[8];
#pragma unroll
    for (int j = 0; j < 8; ++j) acc[j] = 0.f;
    float sw0 = 0.f, sw1 = 0.f;

    const uint4* h16 = (const uint4*)h_bf;
    for (int e0 = start; e0 < end; e0 += 8) {
        int ea = e0 + sub;
        int eb = e0 + 4 + sub;
        bool va = ea < end, vb = eb < end;
        int sa = ssrc[va ? ea : start];
        int sb = ssrc[vb ? eb : start];
        uint4 ra = h16[(size_t)sa * 16 + q];
        uint4 rb = h16[(size_t)sb * 16 + q];
        float xa = als[(size_t)sa * 8 + hd] + ah;
        float xb = als[(size_t)sb * 8 + hd] + ah;
        float ela = xa >= 0.f ? xa : 0.2f * xa;
        float elb = xb >= 0.f ? xb : 0.2f * xb;
        float wa = va ? __expf(ela - mh) : 0.f;
        float wb = vb ? __expf(elb - mh) : 0.f;
        sw0 += wa; sw1 += wb;
#define ULO(u) __uint_as_float((u) << 16)
#define UHI(u) __uint_as_float((u) & 0xffff0000u)
        acc[0] += wa * ULO(ra.x); acc[1] += wa * UHI(ra.x);
        acc[2] += wa * ULO(ra.y); acc[3] += wa * UHI(ra.y);
        acc[4] += wa * ULO(ra.z); acc[5] += wa * UHI(ra.z);
        acc[6] += wa * ULO(ra.w); acc[7] += wa * UHI(ra.w);
        acc[0] += wb * ULO(rb.x); acc[1] += wb * UHI(rb.x);
        acc[2] += wb * ULO(rb.y); acc[3] += wb * UHI(rb.y);
        acc[4] += wb * ULO(rb.z); acc[5] += wb * UHI(rb.z);
        acc[6] += wb * ULO(rb.w); acc[7] += wb * UHI(rb.w);
#undef ULO
#undef UHI
    }
    float sw = sw0 + sw1;
    // sum across the 4 edge slots (lane bits 4,5)
#pragma unroll
    for (int j = 0; j < 8; ++j) {
        acc[j] += __shfl_xor(acc[j], 16, 64);
        acc[j] += __shfl_xor(acc[j], 32, 64);
    }
    sw += __shfl_xor(sw, 16, 64);
    sw += __shfl_xor(sw, 32, 64);
    if (lane < 16) {
        float ish = 1.0f / (sw + 1e-16f);
        const float4* b4 = (const float4*)bias;
        float4 bl = b4[q * 2], bh = b4[q * 2 + 1];
        float4 o0 = {acc[0] * ish + bl.x, acc[1] * ish + bl.y,
                     acc[2] * ish + bl.z, acc[3] * ish + bl.w};
        float4 o1 = {acc[4] * ish + bh.x, acc[5] * ish + bh.y,
                     acc[6] * ish + bh.z, acc[7] * ish + bh.w};
        if (do_relu) {
            o0.x = fmaxf(o0.x, 0.f); o0.y = fmaxf(o0.y, 0.f);
            o0.z = fmaxf(o0.z, 0.f); o0.w = fmaxf(o0.w, 0.f);
            o1.x = fmaxf(o1.x, 0.f); o1.y = fmaxf(o1.y, 0.f);
            o1.z = fmaxf(o1.z, 0.f); o1.w = fmaxf(o1.w, 0.f);
        }
        float4* o4 = (float4*)out;
        o4[(size_t)wid * 32 + q * 2]     = o0;
        o4[(size_t)wid * 32 + q * 2 + 1] = o1;
    }
}

// ------------------------------------------------------------------
// Prediction heads
// ------------------------------------------------------------------
__global__ __launch_bounds__(256) void k_heads(const float* __restrict__ z,
                                               const int* __restrict__ tidx,
                                               const int* __restrict__ cidx,
                                               const float* __restrict__ wy1,
                                               const float* __restrict__ by1,
                                               const float* __restrict__ wy0,
                                               const float* __restrict__ by0,
                                               float* __restrict__ out, int M) {
    int wid  = (blockIdx.x * blockDim.x + threadIdx.x) >> 6;
    int lane = threadIdx.x & 63;
    if (wid >= 2 * M) return;
    int which = (wid >= M) ? 1 : 0;
    int i = wid - which * M;
    int idx = which ? cidx[i] : tidx[i];
    float2 zv = ((const float2*)(z + (size_t)idx * 128))[lane];
    float2 w1 = ((const float2*)wy1)[lane];
    float2 w0 = ((const float2*)wy0)[lane];
    float d1 = zv.x * w1.x + zv.y * w1.y;
    float d0 = zv.x * w0.x + zv.y * w0.y;
#pragma unroll
    for (int off = 32; off > 0; off >>= 1) {
        d1 += __shfl_xor(d1, off, 64);
        d0 += __shfl_xor(d0, off, 64);
    }
    if (lane == 0) {
        float y1v = d1 + by1[0]; y1v = y1v >= 0.f ? y1v : 0.01f * y1v;
        float y0v = d0 + by0[0]; y0v = y0v >= 0.f ? y0v : 0.01f * y0v;
        if (which == 0) { out[i] = y1v; out[M + i] = y0v; }
        else            { out[2 * M + i] = y0v; out[3 * M + i] = y1v; }
    }
}

// ------------------------------------------------------------------
extern "C" void kernel_launch(void* const* d_in, const int* in_sizes, int n_in,
                              void* d_out, int out_size, void* d_ws, size_t ws_size,
                              hipStream_t stream) {
    const float* x   = (const float*)d_in[0];
    const int*   ei  = (const int*)d_in[1];
    const int*   tix = (const int*)d_in[2];
    const int*   cix = (const int*)d_in[3];
    const float* W1  = (const float*)d_in[4];
    const float* as1 = (const float*)d_in[5];
    const float* ad1 = (const float*)d_in[6];
    const float* b1  = (const float*)d_in[7];
    const float* W2  = (const float*)d_in[8];
    const float* as2 = (const float*)d_in[9];
    const float* ad2 = (const float*)d_in[10];
    const float* b2  = (const float*)d_in[11];
    const float* wy1 = (const float*)d_in[12];
    const float* by1 = (const float*)d_in[13];
    const float* wy0 = (const float*)d_in[14];
    const float* by0 = (const float*)d_in[15];
    float* out = (float*)d_out;

    // workspace layout
    float* z_buf     = (float*)d_ws;                  // 12.8M f (xZ1)
    unsigned* h_bf   = (unsigned*)(z_buf + 12800000); // 6.4M u (bf16 h)
    float* als       = (float*)(h_bf + 6400000);      // 800k f
    float* ald       = als + 800000;                  // 800k f
    float* mbuf      = ald + 800000;                  // 800k f
    int* rowptr      = (int*)(mbuf + 800000);         // 100001
    int* bcnt        = rowptr + 100001;               // 392
    int* bucketptr   = bcnt + 392;                    // 392
    int* gcur        = bucketptr + 392;               // 392
    int* ssrc        = gcur + 392;                    // 1.7M
    unsigned* tmp    = (unsigned*)(ssrc + E_TOTC);    // 1.7M

    dim3 B(256);
    // ---- CSR build ----
    k_zero<<<2, B, 0, stream>>>(bcnt, rowptr);
    k_cnt<<<NBC, B, 0, stream>>>(ei, bcnt);
    k_bscan<<<1, dim3(512), 0, stream>>>(bcnt, bucketptr, gcur);
    k_bucket<<<NBA, B, 0, stream>>>(ei, gcur, tmp);
    k_place<<<NBK, B, 0, stream>>>(tmp, bucketptr, rowptr, ssrc);
    // ---- layer 1 ----
    k_gemm_al<<<(N_NODESC + 63) / 64, B, 0, stream>>>(x, W1, as1, ad1, h_bf, als, ald, N_NODESC);
    k_ms<<<(N_NODESC + 31) / 32, B, 0, stream>>>(als, ald, rowptr, ssrc, mbuf, N_NODESC);
    k_agg<<<(N_NODESC + 3) / 4, B, 0, stream>>>(h_bf, als, ald, mbuf, rowptr, ssrc,
                                                b1, z_buf, N_NODESC, 1);
    // ---- layer 2 ----
    k_gemm_al<<<(N_NODESC + 63) / 64, B, 0, stream>>>(z_buf, W2, as2, ad2, h_bf, als, ald, N_NODESC);
    k_ms<<<(N_NODESC + 31) / 32, B, 0, stream>>>(als, ald, rowptr, ssrc, mbuf, N_NODESC);
    k_agg<<<(N_NODESC + 3) / 4, B, 0, stream>>>(h_bf, als, ald, mbuf, rowptr, ssrc,
                                                b2, out + 80000, N_NODESC, 0);
    // ---- heads ----
    k_heads<<<(2 * 20000 * 64) / 256, B, 0, stream>>>(out + 80000, tix, cix,
                                                      wy1, by1, wy0, by0, out, 20000);
}

// Round 6
// 505.194 us; speedup vs baseline: 1.7643x; 1.0644x over previous
//
#include <hip/hip_runtime.h>

#define N_NODESC 100000
#define N_EDGESC 1600000
#define E_TOTC   1700000
#define NBK      391   // dst buckets of 256 nodes
#define EPB      4096  // edges per bucket-phase block
#define NBA      416   // ceil(E_TOTC/EPB)
#define NBC      391   // ceil(N_EDGESC/EPB)

__device__ inline unsigned bf16rne(float x) {
    unsigned u = __float_as_uint(x);
    return (u + 0x7fffu + ((u >> 16) & 1u)) >> 16;
}

// ------------------------------------------------------------------
// CSR build: bucket-count -> bucket-scan -> bucket-scatter -> place
// ------------------------------------------------------------------
__global__ void k_zero(int* bcnt, int* rowptr) {
    int i = blockIdx.x * 256 + threadIdx.x;
    if (i < NBK + 1) bcnt[i] = 0;
    if (i == 0) rowptr[N_NODESC] = E_TOTC;
}

// count real edges per dst-bucket (self-loops added as constants in k_bscan)
__global__ __launch_bounds__(256) void k_cnt(const int* __restrict__ ei, int* bcnt) {
    __shared__ int hist[NBK];
    int t = threadIdx.x;
    for (int i = t; i < NBK; i += 256) hist[i] = 0;
    __syncthreads();
    int e0 = blockIdx.x * EPB;
#pragma unroll
    for (int j = 0; j < 16; ++j) {
        int e = e0 + j * 256 + t;
        if (e < N_EDGESC) atomicAdd(&hist[ei[N_EDGESC + e] >> 8], 1);
    }
    __syncthreads();
    for (int i = t; i < NBK; i += 256) {
        int c = hist[i];
        if (c) atomicAdd(&bcnt[i], c);
    }
}

// exclusive scan of 391 bucket counts (+ per-bucket self-loop constants)
__global__ void k_bscan(const int* __restrict__ bcnt, int* bucketptr, int* gcur) {
    __shared__ int sd[512];
    int t = threadIdx.x;
    int v = 0;
    if (t < NBK) v = bcnt[t] + (t == NBK - 1 ? 160 : 256);  // self-loops per bucket
    sd[t] = v;
    __syncthreads();
    for (int off = 1; off < 512; off <<= 1) {
        int x = (t >= off) ? sd[t - off] : 0;
        __syncthreads();
        sd[t] += x;
        __syncthreads();
    }
    if (t <= NBK) {
        int excl = sd[t] - v;
        bucketptr[t] = excl;
        gcur[t] = excl;
    }
}

// Phase A: scatter edges (+self loops) into bucket-contiguous tmp.
// Payload: s | (dlocal<<20).
__global__ __launch_bounds__(256) void k_bucket(const int* __restrict__ ei,
                                                int* gcur, unsigned* __restrict__ tmp) {
    __shared__ int hist[NBK];
    __shared__ int cnt[NBK];
    __shared__ int base[NBK];
    int t = threadIdx.x;
    for (int i = t; i < NBK; i += 256) { hist[i] = 0; cnt[i] = 0; }
    __syncthreads();

    int e0 = blockIdx.x * EPB;
    int ss[16], dd[16];
#pragma unroll
    for (int j = 0; j < 16; ++j) {
        int e = e0 + j * 256 + t;
        if (e < E_TOTC) {
            if (e < N_EDGESC) { ss[j] = ei[e]; dd[j] = ei[N_EDGESC + e]; }
            else { ss[j] = dd[j] = e - N_EDGESC; }
            atomicAdd(&hist[dd[j] >> 8], 1);
        } else {
            dd[j] = -1;
        }
    }
    __syncthreads();
    for (int i = t; i < NBK; i += 256) {
        int c = hist[i];
        base[i] = c > 0 ? atomicAdd(&gcur[i], c) : 0;
    }
    __syncthreads();
#pragma unroll
    for (int j = 0; j < 16; ++j) {
        if (dd[j] >= 0) {
            int b = dd[j] >> 8;
            int pos = base[b] + atomicAdd(&cnt[b], 1);
            tmp[pos] = (unsigned)ss[j] | ((unsigned)(dd[j] & 255) << 20);
        }
    }
}

// Phase B: one block per bucket. Derives per-node rowptr from tmp
// (LDS count + scan), then places edges into the final ssrc window.
__global__ __launch_bounds__(256) void k_place(const unsigned* __restrict__ tmp,
                                               const int* __restrict__ bucketptr,
                                               int* __restrict__ rowptr,
                                               int* __restrict__ ssrc) {
    __shared__ int cnt256[256];
    __shared__ int sd[256];
    __shared__ int lcur[256];
    int b = blockIdx.x;
    int t = threadIdx.x;
    int rbeg = bucketptr[b];
    int rend = bucketptr[b + 1];
    cnt256[t] = 0;
    __syncthreads();
    for (int e = rbeg + t; e < rend; e += 256)
        atomicAdd(&cnt256[tmp[e] >> 20], 1);
    __syncthreads();
    int v = cnt256[t];
    sd[t] = v;
    __syncthreads();
    for (int off = 1; off < 256; off <<= 1) {
        int x = (t >= off) ? sd[t - off] : 0;
        __syncthreads();
        sd[t] += x;
        __syncthreads();
    }
    int rp = rbeg + sd[t] - v;   // exclusive
    int nd = b * 256 + t;
    if (nd < N_NODESC) rowptr[nd] = rp;
    lcur[t] = rp;
    __syncthreads();
    for (int e = rbeg + t; e < rend; e += 256) {
        unsigned p = tmp[e];
        int pos = atomicAdd(&lcur[p >> 20], 1);
        ssrc[pos] = p & 0xFFFFFu;
    }
}

// ------------------------------------------------------------------
// Fused GEMM + attention logits + bf16 pack.
// ------------------------------------------------------------------
__global__ __launch_bounds__(256) void k_gemm_al(const float* __restrict__ A,
                                                 const float* __restrict__ W,
                                                 const float* __restrict__ a_src,
                                                 const float* __restrict__ a_dst,
                                                 unsigned* __restrict__ h_bf,
                                                 float* __restrict__ als,
                                                 float* __restrict__ ald, int M) {
    __shared__ float Xt[128][64];  // [k][m] 32 KB
    int t = threadIdx.x;
    int mbase = blockIdx.x * 64;
    {
        int r = t & 63;
        int row = mbase + r;
        if (row >= M) row = 0;  // clamp; stores are guarded
        const float4* A4 = (const float4*)A;
#pragma unroll
        for (int j = 0; j < 8; ++j) {
            int k4 = (t >> 6) + j * 4;
            float4 v = A4[(size_t)row * 32 + k4];
            int kf = k4 * 4;
            Xt[kf + 0][r] = v.x;
            Xt[kf + 1][r] = v.y;
            Xt[kf + 2][r] = v.z;
            Xt[kf + 3][r] = v.w;
        }
    }
    __syncthreads();
    int m0 = (t >> 4) * 4;
    int cg = t & 15;          // col-group: cols 8cg..8cg+7
    int n4 = cg * 2;
    float acc[4][8];
#pragma unroll
    for (int i = 0; i < 4; ++i)
#pragma unroll
        for (int j = 0; j < 8; ++j) acc[i][j] = 0.f;
    const float4* W4 = (const float4*)W;
#pragma unroll 4
    for (int k = 0; k < 128; ++k) {
        float4 b0 = W4[k * 32 + n4];
        float4 b1 = W4[k * 32 + n4 + 1];
        float4 a = *(const float4*)&Xt[k][m0];
        float av[4] = {a.x, a.y, a.z, a.w};
        float bv[8] = {b0.x, b0.y, b0.z, b0.w, b1.x, b1.y, b1.z, b1.w};
#pragma unroll
        for (int i = 0; i < 4; ++i)
#pragma unroll
            for (int j = 0; j < 8; ++j) acc[i][j] += av[i] * bv[j];
    }
    // epilogue: bf16 pack + per-head attention logits
    int head  = cg >> 1;
    int half8 = (cg & 1) * 8;
    const float4* asp = (const float4*)(a_src + head * 16 + half8);
    const float4* adp = (const float4*)(a_dst + head * 16 + half8);
    float4 as0 = asp[0], as1 = asp[1];
    float4 ad0 = adp[0], ad1 = adp[1];
    uint4* hb4 = (uint4*)h_bf;
#pragma unroll
    for (int i = 0; i < 4; ++i) {
        int m = mbase + m0 + i;
        float* a8 = acc[i];
        float ps = a8[0]*as0.x + a8[1]*as0.y + a8[2]*as0.z + a8[3]*as0.w
                 + a8[4]*as1.x + a8[5]*as1.y + a8[6]*as1.z + a8[7]*as1.w;
        float pd = a8[0]*ad0.x + a8[1]*ad0.y + a8[2]*ad0.z + a8[3]*ad0.w
                 + a8[4]*ad1.x + a8[5]*ad1.y + a8[6]*ad1.z + a8[7]*ad1.w;
        ps += __shfl_xor(ps, 1, 64);
        pd += __shfl_xor(pd, 1, 64);
        if (m < M) {
            uint4 hb;
            hb.x = bf16rne(a8[0]) | (bf16rne(a8[1]) << 16);
            hb.y = bf16rne(a8[2]) | (bf16rne(a8[3]) << 16);
            hb.z = bf16rne(a8[4]) | (bf16rne(a8[5]) << 16);
            hb.w = bf16rne(a8[6]) | (bf16rne(a8[7]) << 16);
            hb4[(size_t)m * 16 + cg] = hb;
            if ((cg & 1) == 0) {
                als[(size_t)m * 8 + head] = ps;
                ald[(size_t)m * 8 + head] = pd;
            }
        }
    }
}

// ------------------------------------------------------------------
// Weighted aggregation + softmax (no-max exp: |logit| <~6, fp32-safe).
// One wave per dst node; 8 lanes per edge (lane o = head o, 32 B of the
// row via 2 independent uint4 loads) -> 8 edges & 16 h-loads in flight.
// als lookup is one coalesced 32 B segment per edge; 1 exp per (edge,head).
// ------------------------------------------------------------------
__global__ __launch_bounds__(256) void k_agg(const unsigned* __restrict__ h_bf,
                                             const float* __restrict__ als,
                                             const float* __restrict__ ald,
                                             const int* __restrict__ rowptr,
                                             const int* __restrict__ ssrc,
                                             const float* __restrict__ bias,
                                             float* __restrict__ out,
                                             int n, int do_relu) {
    int wid  = (blockIdx.x * blockDim.x + threadIdx.x) >> 6;
    int lane = threadIdx.x & 63;
    if (wid >= n) return;
    int start = rowptr[wid];
    int end   = rowptr[wid + 1];
    int slot = lane >> 3;  // edge slot 0..7
    int o    = lane & 7;   // head; cols 16o..16o+15

    float ah = ald[(size_t)wid * 8 + o];

    float acc[16];
#pragma unroll
    for (int j = 0; j < 16; ++j) acc[j] = 0.f;
    float sw = 0.f;

    const uint4* h16 = (const uint4*)h_bf;
    for (int e0 = start; e0 < end; e0 += 8) {
        int e = e0 + slot;
        bool v = e < end;
        int s = ssrc[v ? e : start];
        uint4 r0 = h16[(size_t)s * 16 + o * 2];
        uint4 r1 = h16[(size_t)s * 16 + o * 2 + 1];
        float xv = als[(size_t)s * 8 + o] + ah;
        float el = xv >= 0.f ? xv : 0.2f * xv;
        float w  = v ? __expf(el) : 0.f;
        sw += w;
#define ULO(u) __uint_as_float((u) << 16)
#define UHI(u) __uint_as_float((u) & 0xffff0000u)
        acc[0]  += w * ULO(r0.x); acc[1]  += w * UHI(r0.x);
        acc[2]  += w * ULO(r0.y); acc[3]  += w * UHI(r0.y);
        acc[4]  += w * ULO(r0.z); acc[5]  += w * UHI(r0.z);
        acc[6]  += w * ULO(r0.w); acc[7]  += w * UHI(r0.w);
        acc[8]  += w * ULO(r1.x); acc[9]  += w * UHI(r1.x);
        acc[10] += w * ULO(r1.y); acc[11] += w * UHI(r1.y);
        acc[12] += w * ULO(r1.z); acc[13] += w * UHI(r1.z);
        acc[14] += w * ULO(r1.w); acc[15] += w * UHI(r1.w);
#undef ULO
#undef UHI
    }
    // reduce across the 8 edge slots (lane bits 3,4,5)
#pragma unroll
    for (int j = 0; j < 16; ++j) {
        acc[j] += __shfl_xor(acc[j], 8, 64);
        acc[j] += __shfl_xor(acc[j], 16, 64);
        acc[j] += __shfl_xor(acc[j], 32, 64);
    }
    sw += __shfl_xor(sw, 8, 64);
    sw += __shfl_xor(sw, 16, 64);
    sw += __shfl_xor(sw, 32, 64);
    if (lane < 8) {
        float ish = 1.0f / (sw + 1e-16f);
        const float4* b4 = (const float4*)bias;
        float4* o4 = (float4*)out;
#pragma unroll
        for (int i = 0; i < 4; ++i) {
            float4 bv = b4[o * 4 + i];
            float4 ov = {acc[i*4+0] * ish + bv.x, acc[i*4+1] * ish + bv.y,
                         acc[i*4+2] * ish + bv.z, acc[i*4+3] * ish + bv.w};
            if (do_relu) {
                ov.x = fmaxf(ov.x, 0.f); ov.y = fmaxf(ov.y, 0.f);
                ov.z = fmaxf(ov.z, 0.f); ov.w = fmaxf(ov.w, 0.f);
            }
            o4[(size_t)wid * 32 + o * 4 + i] = ov;
        }
    }
}

// ------------------------------------------------------------------
// Prediction heads
// ------------------------------------------------------------------
__global__ __launch_bounds__(256) void k_heads(const float* __restrict__ z,
                                               const int* __restrict__ tidx,
                                               const int* __restrict__ cidx,
                                               const float* __restrict__ wy1,
                                               const float* __restrict__ by1,
                                               const float* __restrict__ wy0,
                                               const float* __restrict__ by0,
                                               float* __restrict__ out, int M) {
    int wid  = (blockIdx.x * blockDim.x + threadIdx.x) >> 6;
    int lane = threadIdx.x & 63;
    if (wid >= 2 * M) return;
    int which = (wid >= M) ? 1 : 0;
    int i = wid - which * M;
    int idx = which ? cidx[i] : tidx[i];
    float2 zv = ((const float2*)(z + (size_t)idx * 128))[lane];
    float2 w1 = ((const float2*)wy1)[lane];
    float2 w0 = ((const float2*)wy0)[lane];
    float d1 = zv.x * w1.x + zv.y * w1.y;
    float d0 = zv.x * w0.x + zv.y * w0.y;
#pragma unroll
    for (int off = 32; off > 0; off >>= 1) {
        d1 += __shfl_xor(d1, off, 64);
        d0 += __shfl_xor(d0, off, 64);
    }
    if (lane == 0) {
        float y1v = d1 + by1[0]; y1v = y1v >= 0.f ? y1v : 0.01f * y1v;
        float y0v = d0 + by0[0]; y0v = y0v >= 0.f ? y0v : 0.01f * y0v;
        if (which == 0) { out[i] = y1v; out[M + i] = y0v; }
        else            { out[2 * M + i] = y0v; out[3 * M + i] = y1v; }
    }
}

// ------------------------------------------------------------------
extern "C" void kernel_launch(void* const* d_in, const int* in_sizes, int n_in,
                              void* d_out, int out_size, void* d_ws, size_t ws_size,
                              hipStream_t stream) {
    const float* x   = (const float*)d_in[0];
    const int*   ei  = (const int*)d_in[1];
    const int*   tix = (const int*)d_in[2];
    const int*   cix = (const int*)d_in[3];
    const float* W1  = (const float*)d_in[4];
    const float* as1 = (const float*)d_in[5];
    const float* ad1 = (const float*)d_in[6];
    const float* b1  = (const float*)d_in[7];
    const float* W2  = (const float*)d_in[8];
    const float* as2 = (const float*)d_in[9];
    const float* ad2 = (const float*)d_in[10];
    const float* b2  = (const float*)d_in[11];
    const float* wy1 = (const float*)d_in[12];
    const float* by1 = (const float*)d_in[13];
    const float* wy0 = (const float*)d_in[14];
    const float* by0 = (const float*)d_in[15];
    float* out = (float*)d_out;

    // workspace layout
    float* z_buf     = (float*)d_ws;                  // 12.8M f (xZ1)
    unsigned* h_bf   = (unsigned*)(z_buf + 12800000); // 6.4M u (bf16 h)
    float* als       = (float*)(h_bf + 6400000);      // 800k f
    float* ald       = als + 800000;                  // 800k f
    int* rowptr      = (int*)(ald + 800000);          // 100001
    int* bcnt        = rowptr + 100001;               // 392
    int* bucketptr   = bcnt + 392;                    // 392
    int* gcur        = bucketptr + 392;               // 392
    int* ssrc        = gcur + 392;                    // 1.7M
    unsigned* tmp    = (unsigned*)(ssrc + E_TOTC);    // 1.7M

    dim3 B(256);
    // ---- CSR build ----
    k_zero<<<2, B, 0, stream>>>(bcnt, rowptr);
    k_cnt<<<NBC, B, 0, stream>>>(ei, bcnt);
    k_bscan<<<1, dim3(512), 0, stream>>>(bcnt, bucketptr, gcur);
    k_bucket<<<NBA, B, 0, stream>>>(ei, gcur, tmp);
    k_place<<<NBK, B, 0, stream>>>(tmp, bucketptr, rowptr, ssrc);
    // ---- layer 1 ----
    k_gemm_al<<<(N_NODESC + 63) / 64, B, 0, stream>>>(x, W1, as1, ad1, h_bf, als, ald, N_NODESC);
    k_agg<<<(N_NODESC + 3) / 4, B, 0, stream>>>(h_bf, als, ald, rowptr, ssrc,
                                                b1, z_buf, N_NODESC, 1);
    // ---- layer 2 ----
    k_gemm_al<<<(N_NODESC + 63) / 64, B, 0, stream>>>(z_buf, W2, as2, ad2, h_bf, als, ald, N_NODESC);
    k_agg<<<(N_NODESC + 3) / 4, B, 0, stream>>>(h_bf, als, ald, rowptr, ssrc,
                                                b2, out + 80000, N_NODESC, 0);
    // ---- heads ----
    k_heads<<<(2 * 20000 * 64) / 256, B, 0, stream>>>(out + 80000, tix, cix,
                                                      wy1, by1, wy0, by0, out, 20000);
}